// Round 13
// baseline (320.247 us; speedup 1.0000x reference)
//
#include <hip/hip_runtime.h>
#include <math.h>

#define HW 64
#define PPB 16   // pixblocks per image: block q's 4 waves take rows q+16*wv
#define CSTR 8   // row-counter stride (words) to spread atomics across L2 channels

// f32 fast-raster record: 16 floats = 64 B
// float4 view: q0=(wx0,wy0,wc0,wx1) q1=(wy1,wc1,wx2,wy2) q2=(wc2,zx,zy,zc0) q3=(epsf,epsz,pad,pad)
// z is affine in screen coords: z(x,y) = zx*px + zy*py + zc0 (folded in f64).
struct FaceRasF {
  float wx0, wy0, wc0;
  float wx1, wy1, wc1;
  float wx2, wy2, wc2;
  float zx, zy, zc0;
  float epsf, epsz;
  float pad0, pad1;
};

// transform + ALL zero-init (vnorm, rowcnt, cnt): memset dispatch folded in.
__global__ void k_prep(const float* __restrict__ vert,
                       const float* __restrict__ rot,
                       const float* __restrict__ trans,
                       float* __restrict__ vs_cam,
                       float* __restrict__ vnorm,
                       unsigned* __restrict__ zerobase, int nzero,
                       int B, int V) {
  int i = blockIdx.x * blockDim.x + threadIdx.x;
  if (i < nzero) zerobase[i] = 0u;
  if (i >= B * V) return;
  int b = i / V;
  float x = vert[i * 3 + 0], y = vert[i * 3 + 1], z = vert[i * 3 + 2];
  const float* R = rot + b * 9;
  const float* t = trans + b * 3;
  vs_cam[i * 3 + 0] = ((x * R[0] + y * R[1]) + z * R[2]) + t[0];
  vs_cam[i * 3 + 1] = ((x * R[3] + y * R[4]) + z * R[5]) + t[1];
  vs_cam[i * 3 + 2] = ((x * R[6] + y * R[7]) + z * R[8]) + t[2];
  vnorm[i * 3 + 0] = 0.f;
  vnorm[i * 3 + 1] = 0.f;
  vnorm[i * 3 + 2] = 0.f;
}

// face precompute + DIRECT index-bucket emit (CAP=F exact worst case).
// grid: ((F+255)/256, B) so each wave has uniform b (ballot aggregation).
__global__ void k_facepre(const float* __restrict__ vs_cam,
                          const int* __restrict__ faces,
                          FaceRasF* __restrict__ frasF,
                          float* __restrict__ vnorm,
                          unsigned* __restrict__ rowcnt,
                          unsigned* __restrict__ rowbuk,
                          unsigned CAP, int B, int V, int F) {
  int f = blockIdx.x * blockDim.x + threadIdx.x;
  int b = blockIdx.y;
  bool valid = (f < F);
  int r0 = 1, r1 = 0;
  if (valid) {
    int i = b * F + f;
    int i0 = faces[f * 3 + 0], i1 = faces[f * 3 + 1], i2 = faces[f * 3 + 2];
    const float* c0 = vs_cam + (size_t)(b * V + i0) * 3;
    const float* c1 = vs_cam + (size_t)(b * V + i1) * 3;
    const float* c2 = vs_cam + (size_t)(b * V + i2) * 3;
    float c0x = c0[0], c0y = c0[1], c0z = c0[2];
    float c1x = c1[0], c1y = c1[1], c1z = c1[2];
    float c2x = c2[0], c2y = c2[1], c2z = c2[2];
    float v0x = c0x / c0z, v0y = c0y / c0z;
    float v1x = c1x / c1z, v1y = c1y / c1z;
    float v2x = c2x / c2z, v2y = c2y / c2z;
    float dx0 = v2x - v1x, dy0 = v2y - v1y;   // edge(v1,v2), anchor v1
    float dx1 = v0x - v2x, dy1 = v0y - v2y;   // edge(v2,v0), anchor v2
    float dx2 = v1x - v0x, dy2 = v1y - v0y;   // edge(v0,v1), anchor v0
    float Araw = dx2 * (v2y - v0y) - dy2 * (v2x - v0x);
    float A = (fabsf(Araw) < 1e-8f) ? 1e-8f : Araw;
    double invA = 1.0 / (double)A;
    double wx0 = -(double)dy0 * invA, wy0 = (double)dx0 * invA;
    double wc0 = ((double)dy0 * (double)v1x - (double)dx0 * (double)v1y) * invA;
    double wx1 = -(double)dy1 * invA, wy1 = (double)dx1 * invA;
    double wc1 = ((double)dy1 * (double)v2x - (double)dx1 * (double)v2y) * invA;
    double wx2 = -(double)dy2 * invA, wy2 = (double)dx2 * invA;
    double wc2 = ((double)dy2 * (double)v0x - (double)dx2 * (double)v0y) * invA;
    double m0 = fabs(wx0) + fabs(wy0) + fabs(wc0);
    double m1 = fabs(wx1) + fabs(wy1) + fabs(wc1);
    double m2 = fabs(wx2) + fabs(wy2) + fabs(wc2);
    double mm = fmax(fmax(m0, m1), m2);
    float epsf = fmaxf((float)(6e-7 * mm), 3e-7f);
    float zs = fabsf(c0z) + fabsf(c1z) + fabsf(c2z);
    // budget: w-eval error (epsf) + affine-z fold error (<=3 f32 roundings)
    float epsz = (2.0f * epsf + 4e-6f) * zs;
    // z-plane coefficients in f64: z(x,y) = zx*px + zy*py + zc0
    double zxd = wx0 * (double)c0z + wx1 * (double)c1z + wx2 * (double)c2z;
    double zyd = wy0 * (double)c0z + wy1 * (double)c1z + wy2 * (double)c2z;
    double zcd = wc0 * (double)c0z + wc1 * (double)c1z + wc2 * (double)c2z;
    FaceRasF fr;
    fr.wx0 = (float)wx0; fr.wy0 = (float)wy0; fr.wc0 = (float)wc0;
    fr.wx1 = (float)wx1; fr.wy1 = (float)wy1; fr.wc1 = (float)wc1;
    fr.wx2 = (float)wx2; fr.wy2 = (float)wy2; fr.wc2 = (float)wc2;
    fr.zx = (float)zxd; fr.zy = (float)zyd; fr.zc0 = (float)zcd;
    fr.epsf = epsf; fr.epsz = epsz; fr.pad0 = 0.f; fr.pad1 = 0.f;
    frasF[i] = fr;
    // EXACT y-range of {dmin >= -band} via the barycentric slab:
    // w0+w1+w2 == 1, so dmin>=-b <=> all w_i>=-b, and y = sum w_i*v_iy over that
    // slab has exact extremes vext + b*(3*vext - sum).
    float band = fmaxf(0.202f, 1.6f * epsf);
    if (fabsf(Araw) < 1e-8f) {
      r0 = 0; r1 = 63;            // degenerate clamp: sum(w) != 1, no bound
    } else {
      float vmin = fminf(v0y, fminf(v1y, v2y));
      float vmax = fmaxf(v0y, fmaxf(v1y, v2y));
      float s3 = v0y + v1y + v2y;
      float b1 = band * 1.05f + 1e-4f;        // slack for f32 rounding
      float ylo = vmin + b1 * (3.f * vmin - s3);
      float yhi = vmax + b1 * (3.f * vmax - s3);
      if (yhi < -1.001f || ylo > 1.001f) { r0 = 1; r1 = 0; }
      else {
        r0 = max(0, (int)floorf((ylo + 1.0f) * 31.5f) - 1);
        r1 = min(63, (int)ceilf((yhi + 1.0f) * 31.5f) + 1);
        if (r0 > r1) { r0 = 1; r1 = 0; }
      }
    }
    // face normal -> vertex normal scatter (f32 atomics, fire-and-forget)
    float e1x = c1x - c0x, e1y = c1y - c0y, e1z = c1z - c0z;
    float e2x = c2x - c0x, e2y = c2y - c0y, e2z = c2z - c0z;
    float nx = e1y * e2z - e1z * e2y;
    float ny = e1z * e2x - e1x * e2z;
    float nz = e1x * e2y - e1y * e2x;
    float* vn0 = vnorm + (size_t)(b * V + i0) * 3;
    float* vn1 = vnorm + (size_t)(b * V + i1) * 3;
    float* vn2 = vnorm + (size_t)(b * V + i2) * 3;
    atomicAdd(vn0 + 0, nx); atomicAdd(vn0 + 1, ny); atomicAdd(vn0 + 2, nz);
    atomicAdd(vn1 + 0, nx); atomicAdd(vn1 + 1, ny); atomicAdd(vn1 + 2, nz);
    atomicAdd(vn2 + 0, nx); atomicAdd(vn2 + 1, ny); atomicAdd(vn2 + 2, nz);
  }
  // wave-aggregated bucket append, trimmed to the wave's row union
  int lane = threadIdx.x & 63;
  bool has = valid && r0 <= r1;
  int rmin = has ? r0 : 64, rmax = has ? r1 : -1;
  for (int off = 32; off; off >>= 1) {
    rmin = min(rmin, __shfl_xor(rmin, off));
    rmax = max(rmax, __shfl_xor(rmax, off));
  }
  for (int r = rmin; r <= rmax; ++r) {
    bool in = has && r >= r0 && r <= r1;
    unsigned long long m = __ballot(in);
    if (m == 0ull) continue;
    int row = (b << 6) | r;
    int leader = __ffsll(m) - 1;
    unsigned base = 0;
    if (lane == leader) base = atomicAdd(&rowcnt[row * CSTR], (unsigned)__popcll(m));
    base = (unsigned)__shfl((int)base, leader);
    if (in) {
      unsigned pos = base + (unsigned)__popcll(m & ((1ull << lane) - 1ull));
      rowbuk[(size_t)row * CAP + pos] = (unsigned)f;   // pos < F == CAP always
    }
  }
}

// f32 screened raster: LDS-staged batches + 4 independent accumulator sets;
// stride-16 row assignment + 1-D chunk-fast grid (R12: fixed the CU-queueing
// hotspot that was the R2-R11 ~100us invariant).
__global__ __launch_bounds__(256) void k_raster(
    const FaceRasF* __restrict__ frasF,
    const unsigned* __restrict__ rowcnt,
    const unsigned* __restrict__ rowbuk,
    float4* __restrict__ pc,
    unsigned CAP, int F, int NC, int P) {
  __shared__ float4 lds[4][2][64 * 3];   // [wave][buf][entry*3] = 24 KB
  int bid = blockIdx.x;
  int chunk = bid % NC;                  // chunk-fast: consecutive IDs spread
  int g = bid / NC;
  int b = g / PPB;
  int q = g % PPB;
  int wv = threadIdx.x >> 6;
  int lane = threadIdx.x & 63;
  int y = q + 16 * wv;                   // stride-16 rows: block-level balance
  int x = lane;
  const double step = 2.0 / 63.0;
  double pxd = (x == HW - 1) ? 1.0 : (x * step - 1.0);
  double pyd = (y == HW - 1) ? 1.0 : (y * step - 1.0);
  float pxf = (float)pxd, pyf = (float)pyd;

  // 4 independent accumulator sets (named: rule #20)
  float zmA = INFINITY, zmB = INFINITY, zmC = INFINITY, zmD = INFINITY;
  float weA = 0.f, weB = 0.f, weC = 0.f, weD = 0.f;
  float lsA = 0.f, lsB = 0.f, lsC = 0.f, lsD = 0.f;
  int bsA = 0, bsB = 0, bsC = 0, bsD = 0;
  bool flA = false, flB = false, flC = false, flD = false;

  auto BODYG = [&](float4 r0, float4 r1, float4 r2,
                   float& zm, float& we, float& ls, int& bs, bool& fl) {
    float w0 = fmaf(r0.x, pxf, r0.w);   // == fmaf(wx,px,fmaf(wy,py,wc))
    float w1 = fmaf(r0.y, pxf, r1.x);
    float w2 = fmaf(r0.z, pxf, r1.y);
    float dmin = fminf(fminf(w0, w1), w2);
    float t = fminf(fmaxf(dmin * 100.0f, -30.0f), 0.0f);
    float pr = __expf(t);               // inside -> t=0 -> pr=1 exactly
    float lg = __logf(fmaf(-pr, 0.99999990f, 1.0f));
    ls += (dmin > -0.2f) ? lg : 0.0f;   // dmin<=-0.2 contributes <=2e-9
    float z = fmaf(r1.z, pxf, r1.w);    // z affine: zx*px + zc
    float ef = r2.x, ez = r2.y;
    bool act = dmin > -ef;
    bool ge0 = dmin >= 0.0f;
    bool contend = (z < zm + ez + we) & (z > -ez);
    fl |= act & (fabsf(dmin) < ef) & contend;          // inside-sign ambiguous
    fl |= act & ge0 & (fabsf(z) < ez);                 // z>0 boundary ambiguous
    fl |= act & ge0 & (z > 0.0f) & (fabsf(z - zm) < ez + we); // z-order ambig.
    bool take = act & ge0 & (z > 0.0f) & (z < zm);     // ties repaired in f64
    zm = take ? z : zm;
    bs = take ? __float_as_int(r2.z) : bs;
    we = take ? ez : we;
  };

  int row = (b << 6) | y;                      // wave-uniform: wave = one row
  unsigned fill = rowcnt[row * CSTR];
  const unsigned* __restrict__ rl = rowbuk + (size_t)row * CAP;
  const float4* __restrict__ fb4 = (const float4*)(frasF + (size_t)b * F);
  unsigned per = (fill + (unsigned)NC - 1) / (unsigned)NC;
  unsigned i0 = min(fill, (unsigned)chunk * per);
  unsigned i1 = min(fill, i0 + per);
  if (i0 < i1) {
    // lane-parallel gather (per-lane vector loads, vmcnt-counted): 64 records
    // in ONE memory latency; issued EARLY, LDS-written LATE. OOR lanes -> null.
    float4 g0, g1, g2;
    auto GATHER = [&](unsigned base) {
      unsigned j = base + (unsigned)lane;
      bool ok = (j < i1);
      unsigned jj = ok ? j : (i1 - 1);
      int fidx = (int)rl[jj];
      size_t o = (size_t)fidx * 4;
      float4 q0 = fb4[o + 0], q1 = fb4[o + 1], q2 = fb4[o + 2], q3 = fb4[o + 3];
      float ce0 = fmaf(q0.y, pyf, q0.z);     // wy*py+wc (py wave-uniform)
      float ce1 = fmaf(q1.x, pyf, q1.y);
      float ce2 = fmaf(q1.w, pyf, q2.x);
      float zc  = fmaf(q2.z, pyf, q2.w);     // zy*py+zc0
      // null record for OOR: ce0=-1e30 -> dmin=-1e30 -> all gates false
      g0 = make_float4(ok ? q0.x : 0.f, ok ? q0.w : 0.f, ok ? q1.z : 0.f,
                       ok ? ce0 : -1e30f);
      g1 = make_float4(ok ? ce1 : 0.f, ok ? ce2 : 0.f, ok ? q2.y : 0.f,
                       ok ? zc : 0.f);
      g2 = make_float4(ok ? q3.x : 0.f, ok ? q3.y : 0.f,
                       __int_as_float(ok ? fidx : 0), 0.f);
    };
    auto WRITE = [&](int buf) {
      lds[wv][buf][lane * 3 + 0] = g0;
      lds[wv][buf][lane * 3 + 1] = g1;
      lds[wv][buf][lane * 3 + 2] = g2;
    };
    GATHER(i0);
    WRITE(0);
    unsigned nb = (i1 - i0 + 63) >> 6;
    for (unsigned bi = 0; bi < nb; ++bi) {
      if (bi + 1 < nb) GATHER(i0 + (bi + 1) * 64);   // next batch in flight
      int n = (int)min(64u, i1 - i0 - bi * 64);
      int n4 = (n + 3) & ~3;                         // pad to group of 4 (nulls)
      const float4* __restrict__ L = lds[wv][bi & 1];
      for (int k = 0; k < n4; k += 4) {
        // 12 named loads first (ds_reads batch-issued), then 4 indep chains
        float4 a0 = L[(k+0)*3+0], a1 = L[(k+0)*3+1], a2 = L[(k+0)*3+2];
        float4 b0 = L[(k+1)*3+0], b1 = L[(k+1)*3+1], b2 = L[(k+1)*3+2];
        float4 c0 = L[(k+2)*3+0], c1 = L[(k+2)*3+1], c2 = L[(k+2)*3+2];
        float4 d0 = L[(k+3)*3+0], d1 = L[(k+3)*3+1], d2 = L[(k+3)*3+2];
        BODYG(a0, a1, a2, zmA, weA, lsA, bsA, flA);
        BODYG(b0, b1, b2, zmB, weB, lsB, bsB, flB);
        BODYG(c0, c1, c2, zmC, weC, lsC, bsC, flC);
        BODYG(d0, d1, d2, zmD, weD, lsD, bsD, flD);
      }
      if (bi + 1 < nb) WRITE((bi + 1) & 1);          // write after walk
    }
  }
  // merge the 4 partials with the k_final cross-chunk rules (NaN-safe)
  float zmin = INFINITY, weps = 0.f, lsum = 0.f;
  int best = 0;
  bool flag = false;
  auto MERGE = [&](float z, float e, float l, int bsx, bool flx) {
    flag |= flx;
    flag |= fabsf(z - zmin) < (e + weps + 2e-6f);
    if (z < zmin) { zmin = z; best = bsx; weps = e; }
    lsum += l;
  };
  MERGE(zmA, weA, lsA, bsA, flA);
  MERGE(zmB, weB, lsB, bsB, flB);
  MERGE(zmC, weC, lsC, bsC, flC);
  MERGE(zmD, weD, lsD, bsD, flD);
  int p = b * (HW * HW) + (y << 6) + x;
  unsigned pbv = (unsigned)best | (flag ? 0x80000000u : 0u);
  pc[(size_t)chunk * P + p] = make_float4(zmin, lsum, weps, __uint_as_float(pbv));
}

// exact f64 winner recompute + gather-interpolate + output write (not improb)
__device__ void write_winner(const float* __restrict__ vs_cam,
                             const int* __restrict__ faces,
                             const float* __restrict__ vnorm,
                             const float* __restrict__ attribs,
                             float* __restrict__ out, int P,
                             int b, int V, int F, int pix,
                             int best, bool covered) {
  int p = b * (HW * HW) + pix;
  float imn[3] = {0.f, 0.f, 0.f};
  float ima[3] = {0.f, 0.f, 0.f};
  if (covered) {
    int x = pix & 63, y = pix >> 6;
    const double step = 2.0 / 63.0;
    double px = (x == HW - 1) ? 1.0 : (x * step - 1.0);
    double py = (y == HW - 1) ? 1.0 : (y * step - 1.0);
    int vid[3] = {faces[best * 3 + 0], faces[best * 3 + 1], faces[best * 3 + 2]};
    const float* c0 = vs_cam + (size_t)(b * V + vid[0]) * 3;
    const float* c1 = vs_cam + (size_t)(b * V + vid[1]) * 3;
    const float* c2 = vs_cam + (size_t)(b * V + vid[2]) * 3;
    float v0x = c0[0] / c0[2], v0y = c0[1] / c0[2];
    float v1x = c1[0] / c1[2], v1y = c1[1] / c1[2];
    float v2x = c2[0] / c2[2], v2y = c2[1] / c2[2];
    float dx0 = v2x - v1x, dy0 = v2y - v1y;
    float dx1 = v0x - v2x, dy1 = v0y - v2y;
    float dx2 = v1x - v0x, dy2 = v1y - v0y;
    float A = dx2 * (v2y - v0y) - dy2 * (v2x - v0x);
    if (fabsf(A) < 1e-8f) A = 1e-8f;
    double invA = 1.0 / (double)A;
    double a0 = (double)dx0 * (py - (double)v1y) - (double)dy0 * (px - (double)v1x);
    double a1 = (double)dx1 * (py - (double)v2y) - (double)dy1 * (px - (double)v2x);
    double a2 = (double)dx2 * (py - (double)v0y) - (double)dy2 * (px - (double)v0x);
    double wk[3] = {a0 * invA, a1 * invA, a2 * invA};
    double v[6] = {0, 0, 0, 0, 0, 0};
#pragma unroll
    for (int k = 0; k < 3; ++k) {
      const float* n = vnorm + (size_t)(b * V + vid[k]) * 3;
      float nx = n[0], ny = n[1], nz = n[2];
      float nrm = sqrtf(nx * nx + ny * ny + nz * nz) + 1e-10f;  // f32, like ref
      const float* at = attribs + (((size_t)(b * F + best)) * 3 + k) * 3;
      v[0] += wk[k] * (double)(nx / nrm);
      v[1] += wk[k] * (double)(ny / nrm);
      v[2] += wk[k] * (double)(nz / nrm);
      v[3] += wk[k] * (double)at[0];
      v[4] += wk[k] * (double)at[1];
      v[5] += wk[k] * (double)at[2];
    }
    double nn = sqrt(v[0] * v[0] + v[1] * v[1] + v[2] * v[2]) + 1e-10;
    imn[0] = (float)(v[0] / nn);
    imn[1] = (float)(v[1] / nn);
    imn[2] = (float)(v[2] / nn);
    ima[0] = (float)v[3]; ima[1] = (float)v[4]; ima[2] = (float)v[5];
  }
  float* o_n = out;
  float* o_a = out + (size_t)P * 3;
  float* o_p = out + (size_t)P * 6;
  float* o_i = o_p + P;
  o_n[(size_t)p * 3 + 0] = imn[0];
  o_n[(size_t)p * 3 + 1] = imn[1];
  o_n[(size_t)p * 3 + 2] = imn[2];
  o_a[(size_t)p * 3 + 0] = ima[0];
  o_a[(size_t)p * 3 + 1] = ima[1];
  o_a[(size_t)p * 3 + 2] = ima[2];
  o_i[p] = covered ? (float)best : -1.0f;
}

__global__ void k_final(const float* __restrict__ vs_cam,
                        const int* __restrict__ faces,
                        const float* __restrict__ vnorm,
                        const float* __restrict__ attribs,
                        const float4* __restrict__ pc,
                        float* __restrict__ out,
                        int* __restrict__ cnt, int* __restrict__ list,
                        int B, int V, int F, int NC) {
  int p = blockIdx.x * blockDim.x + threadIdx.x;
  int P = B * HW * HW;
  if (p >= P) return;
  float zmin = INFINITY, weps = 0.f, lsum = 0.f;
  int best = 0;
  bool flag = false;
  for (int c = 0; c < NC; ++c) {
    float4 q = pc[(size_t)c * P + p];
    float z = q.x;
    float e = q.z;
    unsigned pb = __float_as_uint(q.w);
    flag |= (pb >> 31) != 0;
    flag |= fabsf(z - zmin) < (e + weps + 2e-6f);  // cross-chunk near-tie (NaN-safe)
    if (z < zmin) { zmin = z; best = (int)(pb & 0x7fffffffu); weps = e; }
    lsum += q.y;
  }
  bool covered = (zmin < 1e38f);
  int b = p >> 12;            // HW*HW = 4096
  int pix = p & 4095;
  write_winner(vs_cam, faces, vnorm, attribs, out, P, b, V, F, pix, best, covered);
  float* o_p = out + (size_t)P * 6;
  o_p[p] = 1.0f - __expf(lsum);
  if (flag) {
    int s = atomicAdd(cnt, 1);
    list[s] = p;
  }
}

// exact f64 re-argmin for flagged pixels: one wave per pixel.
// R12 PMC: this was the new leader (71us, VALUBusy 3%, occ 1.2%) — it walked
// ALL F faces in f64 with dependent gathers. Now: walk the pixel row's BUCKET
// (complete for exact-inside faces: dmin>=0 > -band, same completeness k_raster
// relies on) and SCREEN with the f32 record first (exact-inside => f64 dmin>=0
// => record dmin >= -epsf, the bound epsf was built for). ~1-3% pass to f64.
__global__ __launch_bounds__(256) void k_repair(
    const float* __restrict__ vs_cam,
    const int* __restrict__ faces,
    const float* __restrict__ vnorm,
    const float* __restrict__ attribs,
    const FaceRasF* __restrict__ frasF,
    const unsigned* __restrict__ rowcnt,
    const unsigned* __restrict__ rowbuk,
    const int* __restrict__ cnt, const int* __restrict__ list,
    float* __restrict__ out, unsigned CAP, int B, int V, int F) {
  int P = B * HW * HW;
  int gtid = blockIdx.x * blockDim.x + threadIdx.x;
  int wid = gtid >> 6;
  int lane = threadIdx.x & 63;
  int nwaves = (gridDim.x * blockDim.x) >> 6;
  int n = cnt[0];
  for (int i = wid; i < n; i += nwaves) {
    int p = list[i];
    int b = p >> 12;
    int pix = p & 4095;
    int x = pix & 63, y = pix >> 6;
    const double step = 2.0 / 63.0;
    double px = (x == HW - 1) ? 1.0 : (x * step - 1.0);
    double py = (y == HW - 1) ? 1.0 : (y * step - 1.0);
    float pxf = (float)px, pyf = (float)py;
    int row = (b << 6) | y;
    unsigned fill = rowcnt[row * CSTR];
    const unsigned* __restrict__ rl = rowbuk + (size_t)row * CAP;
    const float4* __restrict__ fb4 = (const float4*)(frasF + (size_t)b * F);
    double zmin = INFINITY;
    int best = 0x7fffffff;
    for (unsigned j = lane; j < fill; j += 64) {
      int f = (int)rl[j];
      size_t o = (size_t)f * 4;
      float4 q0 = fb4[o + 0], q1 = fb4[o + 1], q2 = fb4[o + 2], q3 = fb4[o + 3];
      float w0f = fmaf(q0.x, pxf, fmaf(q0.y, pyf, q0.z));
      float w1f = fmaf(q0.w, pxf, fmaf(q1.x, pyf, q1.y));
      float w2f = fmaf(q1.z, pxf, fmaf(q1.w, pyf, q2.x));
      float dminf = fminf(fminf(w0f, w1f), w2f);
      if (dminf <= -q3.x) continue;          // sound screen: cannot be inside
      int i0 = faces[f * 3 + 0], i1 = faces[f * 3 + 1], i2 = faces[f * 3 + 2];
      const float* c0 = vs_cam + (size_t)(b * V + i0) * 3;
      const float* c1 = vs_cam + (size_t)(b * V + i1) * 3;
      const float* c2 = vs_cam + (size_t)(b * V + i2) * 3;
      float c0z = c0[2], c1z = c1[2], c2z = c2[2];
      float v0x = c0[0] / c0z, v0y = c0[1] / c0z;
      float v1x = c1[0] / c1z, v1y = c1[1] / c1z;
      float v2x = c2[0] / c2z, v2y = c2[1] / c2z;
      float dx0 = v2x - v1x, dy0 = v2y - v1y;
      float dx1 = v0x - v2x, dy1 = v0y - v2y;
      float dx2 = v1x - v0x, dy2 = v1y - v0y;
      float A = dx2 * (v2y - v0y) - dy2 * (v2x - v0x);
      if (fabsf(A) < 1e-8f) A = 1e-8f;
      double invA = 1.0 / (double)A;
      double a0 = (double)dx0 * (py - (double)v1y) - (double)dy0 * (px - (double)v1x);
      double a1 = (double)dx1 * (py - (double)v2y) - (double)dy1 * (px - (double)v2x);
      double a2 = (double)dx2 * (py - (double)v0y) - (double)dy2 * (px - (double)v0x);
      double w0 = a0 * invA, w1 = a1 * invA, w2 = a2 * invA;
      bool inside = (w0 >= 0.0) & (w1 >= 0.0) & (w2 >= 0.0);
      double z = (w0 * (double)c0z + w1 * (double)c1z) + w2 * (double)c2z;
      // bucket order is arbitrary -> in-lane lexicographic (z, idx) for
      // first-occurrence argmin semantics
      if (inside & (z > 0.0) & ((z < zmin) | ((z == zmin) & (f < best)))) {
        zmin = z; best = f;
      }
    }
    // lexicographic (z, idx) wave reduce -> first-occurrence argmin
    for (int off = 32; off; off >>= 1) {
      double zo = __shfl_down(zmin, off);
      int bo = __shfl_down(best, off);
      if ((zo < zmin) || ((zo == zmin) && (bo < best))) { zmin = zo; best = bo; }
    }
    if (lane == 0) {
      bool covered = (zmin < 1e300);
      write_winner(vs_cam, faces, vnorm, attribs, out, P, b, V, F, pix, best, covered);
    }
  }
}

extern "C" void kernel_launch(void* const* d_in, const int* in_sizes, int n_in,
                              void* d_out, int out_size, void* d_ws, size_t ws_size,
                              hipStream_t stream) {
  const float* vert    = (const float*)d_in[0];
  const int*   faces   = (const int*)d_in[1];
  const float* attribs = (const float*)d_in[2];
  const float* rot     = (const float*)d_in[3];
  const float* trans   = (const float*)d_in[4];
  int B = in_sizes[4] / 3;
  int V = in_sizes[0] / (3 * B);
  int F = in_sizes[1] / 3;
  int P = B * HW * HW;
  int NR = B * HW;                              // total (b,row) buckets

  size_t CAP = (size_t)F;                       // exact worst case, no overflow
  size_t szFras  = sizeof(FaceRasF) * (size_t)B * F;
  size_t szBuk   = 4ull * (size_t)NR * CAP;
  size_t szVs    = 12ull * (size_t)B * V;
  size_t szVn    = 12ull * (size_t)B * V;
  size_t szRowC  = 4ull * (size_t)NR * CSTR;    // rowcnt (strided)
  size_t szCnt   = 4;
  size_t szPlist = 4ull * (size_t)P;
  size_t fixed   = szFras + szBuk + szVs + szVn + szRowC + szCnt + szPlist + 1024;

  int NC = 32;                                  // chunks
  while (NC > 2 && fixed + (size_t)P * 16ull * NC > ws_size) NC >>= 1;

  char* w = (char*)d_ws;
  FaceRasF* frasF  = (FaceRasF*)w; w += szFras;            // 64B-aligned
  float4* pc       = (float4*)w;   w += (size_t)P * 16ull * NC;
  unsigned* rowbuk = (unsigned*)w; w += szBuk;
  float* vs_cam    = (float*)w;    w += szVs;
  float* vnorm     = (float*)w;    w += szVn;
  unsigned* rowcnt = (unsigned*)w; w += szRowC;            // contiguous zero region:
  int* cnt         = (int*)w;      w += szCnt;             //   rowcnt + cnt
  int* list        = (int*)w;      /* P entries */
  int nzero = NR * CSTR + 1;

  k_prep<<<(B * V + 255) / 256, 256, 0, stream>>>(vert, rot, trans, vs_cam,
                                                  vnorm, rowcnt, nzero, B, V);
  dim3 fg((unsigned)((F + 255) / 256), (unsigned)B);
  k_facepre<<<fg, 256, 0, stream>>>(vs_cam, faces, frasF, vnorm, rowcnt,
                                    rowbuk, (unsigned)CAP, B, V, F);
  // 1-D chunk-fast grid: consecutive block IDs = chunks of the same pixgrp,
  // spread across CUs/XCDs; stride-16 rows inside blocks balance the rest.
  k_raster<<<(unsigned)(B * PPB * NC), 256, 0, stream>>>(frasF, rowcnt, rowbuk,
                                                         pc, (unsigned)CAP, F,
                                                         NC, P);
  k_final<<<(P + 255) / 256, 256, 0, stream>>>(vs_cam, faces, vnorm, attribs,
                                               pc, (float*)d_out, cnt, list,
                                               B, V, F, NC);
  k_repair<<<1024, 256, 0, stream>>>(vs_cam, faces, vnorm, attribs, frasF,
                                     rowcnt, rowbuk, cnt, list,
                                     (float*)d_out, (unsigned)CAP, B, V, F);
}

// Round 14
// 301.002 us; speedup vs baseline: 1.0639x; 1.0639x over previous
//
#include <hip/hip_runtime.h>
#include <math.h>

#define HW 64
#define PPB 16   // pixblocks per image: block q's 4 waves take rows q+16*wv
#define CSTR 8   // row-counter stride (words) to spread atomics across L2 channels

// f32 fast-raster record: 16 floats = 64 B
// float4 view: q0=(wx0,wy0,wc0,wx1) q1=(wy1,wc1,wx2,wy2) q2=(wc2,zx,zy,zc0) q3=(epsf,epsz,pad,pad)
// z is affine in screen coords: z(x,y) = zx*px + zy*py + zc0 (folded in f64).
struct FaceRasF {
  float wx0, wy0, wc0;
  float wx1, wy1, wc1;
  float wx2, wy2, wc2;
  float zx, zy, zc0;
  float epsf, epsz;
  float pad0, pad1;
};

// transform + ALL zero-init (vnorm, rowcnt, cnt): memset dispatch folded in.
__global__ void k_prep(const float* __restrict__ vert,
                       const float* __restrict__ rot,
                       const float* __restrict__ trans,
                       float* __restrict__ vs_cam,
                       float* __restrict__ vnorm,
                       unsigned* __restrict__ zerobase, int nzero,
                       int B, int V) {
  int i = blockIdx.x * blockDim.x + threadIdx.x;
  if (i < nzero) zerobase[i] = 0u;
  if (i >= B * V) return;
  int b = i / V;
  float x = vert[i * 3 + 0], y = vert[i * 3 + 1], z = vert[i * 3 + 2];
  const float* R = rot + b * 9;
  const float* t = trans + b * 3;
  vs_cam[i * 3 + 0] = ((x * R[0] + y * R[1]) + z * R[2]) + t[0];
  vs_cam[i * 3 + 1] = ((x * R[3] + y * R[4]) + z * R[5]) + t[1];
  vs_cam[i * 3 + 2] = ((x * R[6] + y * R[7]) + z * R[8]) + t[2];
  vnorm[i * 3 + 0] = 0.f;
  vnorm[i * 3 + 1] = 0.f;
  vnorm[i * 3 + 2] = 0.f;
}

// face precompute + DIRECT index-bucket emit (CAP=F exact worst case).
// grid: ((F+255)/256, B) so each wave has uniform b (ballot aggregation).
__global__ void k_facepre(const float* __restrict__ vs_cam,
                          const int* __restrict__ faces,
                          FaceRasF* __restrict__ frasF,
                          float* __restrict__ vnorm,
                          unsigned* __restrict__ rowcnt,
                          unsigned* __restrict__ rowbuk,
                          unsigned CAP, int B, int V, int F) {
  int f = blockIdx.x * blockDim.x + threadIdx.x;
  int b = blockIdx.y;
  bool valid = (f < F);
  int r0 = 1, r1 = 0;
  if (valid) {
    int i = b * F + f;
    int i0 = faces[f * 3 + 0], i1 = faces[f * 3 + 1], i2 = faces[f * 3 + 2];
    const float* c0 = vs_cam + (size_t)(b * V + i0) * 3;
    const float* c1 = vs_cam + (size_t)(b * V + i1) * 3;
    const float* c2 = vs_cam + (size_t)(b * V + i2) * 3;
    float c0x = c0[0], c0y = c0[1], c0z = c0[2];
    float c1x = c1[0], c1y = c1[1], c1z = c1[2];
    float c2x = c2[0], c2y = c2[1], c2z = c2[2];
    float v0x = c0x / c0z, v0y = c0y / c0z;
    float v1x = c1x / c1z, v1y = c1y / c1z;
    float v2x = c2x / c2z, v2y = c2y / c2z;
    float dx0 = v2x - v1x, dy0 = v2y - v1y;   // edge(v1,v2), anchor v1
    float dx1 = v0x - v2x, dy1 = v0y - v2y;   // edge(v2,v0), anchor v2
    float dx2 = v1x - v0x, dy2 = v1y - v0y;   // edge(v0,v1), anchor v0
    float Araw = dx2 * (v2y - v0y) - dy2 * (v2x - v0x);
    float A = (fabsf(Araw) < 1e-8f) ? 1e-8f : Araw;
    double invA = 1.0 / (double)A;
    double wx0 = -(double)dy0 * invA, wy0 = (double)dx0 * invA;
    double wc0 = ((double)dy0 * (double)v1x - (double)dx0 * (double)v1y) * invA;
    double wx1 = -(double)dy1 * invA, wy1 = (double)dx1 * invA;
    double wc1 = ((double)dy1 * (double)v2x - (double)dx1 * (double)v2y) * invA;
    double wx2 = -(double)dy2 * invA, wy2 = (double)dx2 * invA;
    double wc2 = ((double)dy2 * (double)v0x - (double)dx2 * (double)v0y) * invA;
    double m0 = fabs(wx0) + fabs(wy0) + fabs(wc0);
    double m1 = fabs(wx1) + fabs(wy1) + fabs(wc1);
    double m2 = fabs(wx2) + fabs(wy2) + fabs(wc2);
    double mm = fmax(fmax(m0, m1), m2);
    float epsf = fmaxf((float)(6e-7 * mm), 3e-7f);
    float zs = fabsf(c0z) + fabsf(c1z) + fabsf(c2z);
    // budget: w-eval error (epsf) + affine-z fold error (<=3 f32 roundings)
    float epsz = (2.0f * epsf + 4e-6f) * zs;
    // z-plane coefficients in f64: z(x,y) = zx*px + zy*py + zc0
    double zxd = wx0 * (double)c0z + wx1 * (double)c1z + wx2 * (double)c2z;
    double zyd = wy0 * (double)c0z + wy1 * (double)c1z + wy2 * (double)c2z;
    double zcd = wc0 * (double)c0z + wc1 * (double)c1z + wc2 * (double)c2z;
    FaceRasF fr;
    fr.wx0 = (float)wx0; fr.wy0 = (float)wy0; fr.wc0 = (float)wc0;
    fr.wx1 = (float)wx1; fr.wy1 = (float)wy1; fr.wc1 = (float)wc1;
    fr.wx2 = (float)wx2; fr.wy2 = (float)wy2; fr.wc2 = (float)wc2;
    fr.zx = (float)zxd; fr.zy = (float)zyd; fr.zc0 = (float)zcd;
    fr.epsf = epsf; fr.epsz = epsz; fr.pad0 = 0.f; fr.pad1 = 0.f;
    frasF[i] = fr;
    // EXACT y-range of {dmin >= -band} via the barycentric slab:
    // w0+w1+w2 == 1, so dmin>=-b <=> all w_i>=-b, and y = sum w_i*v_iy over that
    // slab has exact extremes vext + b*(3*vext - sum).
    float band = fmaxf(0.202f, 1.6f * epsf);
    if (fabsf(Araw) < 1e-8f) {
      r0 = 0; r1 = 63;            // degenerate clamp: sum(w) != 1, no bound
    } else {
      float vmin = fminf(v0y, fminf(v1y, v2y));
      float vmax = fmaxf(v0y, fmaxf(v1y, v2y));
      float s3 = v0y + v1y + v2y;
      float b1 = band * 1.05f + 1e-4f;        // slack for f32 rounding
      float ylo = vmin + b1 * (3.f * vmin - s3);
      float yhi = vmax + b1 * (3.f * vmax - s3);
      if (yhi < -1.001f || ylo > 1.001f) { r0 = 1; r1 = 0; }
      else {
        r0 = max(0, (int)floorf((ylo + 1.0f) * 31.5f) - 1);
        r1 = min(63, (int)ceilf((yhi + 1.0f) * 31.5f) + 1);
        if (r0 > r1) { r0 = 1; r1 = 0; }
      }
    }
    // face normal -> vertex normal scatter (f32 atomics, fire-and-forget)
    float e1x = c1x - c0x, e1y = c1y - c0y, e1z = c1z - c0z;
    float e2x = c2x - c0x, e2y = c2y - c0y, e2z = c2z - c0z;
    float nx = e1y * e2z - e1z * e2y;
    float ny = e1z * e2x - e1x * e2z;
    float nz = e1x * e2y - e1y * e2x;
    float* vn0 = vnorm + (size_t)(b * V + i0) * 3;
    float* vn1 = vnorm + (size_t)(b * V + i1) * 3;
    float* vn2 = vnorm + (size_t)(b * V + i2) * 3;
    atomicAdd(vn0 + 0, nx); atomicAdd(vn0 + 1, ny); atomicAdd(vn0 + 2, nz);
    atomicAdd(vn1 + 0, nx); atomicAdd(vn1 + 1, ny); atomicAdd(vn1 + 2, nz);
    atomicAdd(vn2 + 0, nx); atomicAdd(vn2 + 1, ny); atomicAdd(vn2 + 2, nz);
  }
  // wave-aggregated bucket append, trimmed to the wave's row union
  int lane = threadIdx.x & 63;
  bool has = valid && r0 <= r1;
  int rmin = has ? r0 : 64, rmax = has ? r1 : -1;
  for (int off = 32; off; off >>= 1) {
    rmin = min(rmin, __shfl_xor(rmin, off));
    rmax = max(rmax, __shfl_xor(rmax, off));
  }
  for (int r = rmin; r <= rmax; ++r) {
    bool in = has && r >= r0 && r <= r1;
    unsigned long long m = __ballot(in);
    if (m == 0ull) continue;
    int row = (b << 6) | r;
    int leader = __ffsll(m) - 1;
    unsigned base = 0;
    if (lane == leader) base = atomicAdd(&rowcnt[row * CSTR], (unsigned)__popcll(m));
    base = (unsigned)__shfl((int)base, leader);
    if (in) {
      unsigned pos = base + (unsigned)__popcll(m & ((1ull << lane) - 1ull));
      rowbuk[(size_t)row * CAP + pos] = (unsigned)f;   // pos < F == CAP always
    }
  }
}

// f32 screened raster: LDS-staged batches + 4 independent accumulator sets;
// stride-16 row assignment + 1-D chunk-fast grid (R12: fixed the CU-queueing
// hotspot that was the R2-R11 ~100us invariant).
__global__ __launch_bounds__(256) void k_raster(
    const FaceRasF* __restrict__ frasF,
    const unsigned* __restrict__ rowcnt,
    const unsigned* __restrict__ rowbuk,
    float4* __restrict__ pc,
    unsigned CAP, int F, int NC, int P) {
  __shared__ float4 lds[4][2][64 * 3];   // [wave][buf][entry*3] = 24 KB
  int bid = blockIdx.x;
  int chunk = bid % NC;                  // chunk-fast: consecutive IDs spread
  int g = bid / NC;
  int b = g / PPB;
  int q = g % PPB;
  int wv = threadIdx.x >> 6;
  int lane = threadIdx.x & 63;
  int y = q + 16 * wv;                   // stride-16 rows: block-level balance
  int x = lane;
  const double step = 2.0 / 63.0;
  double pxd = (x == HW - 1) ? 1.0 : (x * step - 1.0);
  double pyd = (y == HW - 1) ? 1.0 : (y * step - 1.0);
  float pxf = (float)pxd, pyf = (float)pyd;

  // 4 independent accumulator sets (named: rule #20)
  float zmA = INFINITY, zmB = INFINITY, zmC = INFINITY, zmD = INFINITY;
  float weA = 0.f, weB = 0.f, weC = 0.f, weD = 0.f;
  float lsA = 0.f, lsB = 0.f, lsC = 0.f, lsD = 0.f;
  int bsA = 0, bsB = 0, bsC = 0, bsD = 0;
  bool flA = false, flB = false, flC = false, flD = false;

  auto BODYG = [&](float4 r0, float4 r1, float4 r2,
                   float& zm, float& we, float& ls, int& bs, bool& fl) {
    float w0 = fmaf(r0.x, pxf, r0.w);   // == fmaf(wx,px,fmaf(wy,py,wc))
    float w1 = fmaf(r0.y, pxf, r1.x);
    float w2 = fmaf(r0.z, pxf, r1.y);
    float dmin = fminf(fminf(w0, w1), w2);
    float t = fminf(fmaxf(dmin * 100.0f, -30.0f), 0.0f);
    float pr = __expf(t);               // inside -> t=0 -> pr=1 exactly
    float lg = __logf(fmaf(-pr, 0.99999990f, 1.0f));
    ls += (dmin > -0.2f) ? lg : 0.0f;   // dmin<=-0.2 contributes <=2e-9
    float z = fmaf(r1.z, pxf, r1.w);    // z affine: zx*px + zc
    float ef = r2.x, ez = r2.y;
    bool act = dmin > -ef;
    bool ge0 = dmin >= 0.0f;
    bool contend = (z < zm + ez + we) & (z > -ez);
    fl |= act & (fabsf(dmin) < ef) & contend;          // inside-sign ambiguous
    fl |= act & ge0 & (fabsf(z) < ez);                 // z>0 boundary ambiguous
    fl |= act & ge0 & (z > 0.0f) & (fabsf(z - zm) < ez + we); // z-order ambig.
    bool take = act & ge0 & (z > 0.0f) & (z < zm);     // ties repaired in f64
    zm = take ? z : zm;
    bs = take ? __float_as_int(r2.z) : bs;
    we = take ? ez : we;
  };

  int row = (b << 6) | y;                      // wave-uniform: wave = one row
  unsigned fill = rowcnt[row * CSTR];
  const unsigned* __restrict__ rl = rowbuk + (size_t)row * CAP;
  const float4* __restrict__ fb4 = (const float4*)(frasF + (size_t)b * F);
  unsigned per = (fill + (unsigned)NC - 1) / (unsigned)NC;
  unsigned i0 = min(fill, (unsigned)chunk * per);
  unsigned i1 = min(fill, i0 + per);
  if (i0 < i1) {
    // lane-parallel gather (per-lane vector loads, vmcnt-counted): 64 records
    // in ONE memory latency; issued EARLY, LDS-written LATE. OOR lanes -> null.
    float4 g0, g1, g2;
    auto GATHER = [&](unsigned base) {
      unsigned j = base + (unsigned)lane;
      bool ok = (j < i1);
      unsigned jj = ok ? j : (i1 - 1);
      int fidx = (int)rl[jj];
      size_t o = (size_t)fidx * 4;
      float4 q0 = fb4[o + 0], q1 = fb4[o + 1], q2 = fb4[o + 2], q3 = fb4[o + 3];
      float ce0 = fmaf(q0.y, pyf, q0.z);     // wy*py+wc (py wave-uniform)
      float ce1 = fmaf(q1.x, pyf, q1.y);
      float ce2 = fmaf(q1.w, pyf, q2.x);
      float zc  = fmaf(q2.z, pyf, q2.w);     // zy*py+zc0
      // null record for OOR: ce0=-1e30 -> dmin=-1e30 -> all gates false
      g0 = make_float4(ok ? q0.x : 0.f, ok ? q0.w : 0.f, ok ? q1.z : 0.f,
                       ok ? ce0 : -1e30f);
      g1 = make_float4(ok ? ce1 : 0.f, ok ? ce2 : 0.f, ok ? q2.y : 0.f,
                       ok ? zc : 0.f);
      g2 = make_float4(ok ? q3.x : 0.f, ok ? q3.y : 0.f,
                       __int_as_float(ok ? fidx : 0), 0.f);
    };
    auto WRITE = [&](int buf) {
      lds[wv][buf][lane * 3 + 0] = g0;
      lds[wv][buf][lane * 3 + 1] = g1;
      lds[wv][buf][lane * 3 + 2] = g2;
    };
    GATHER(i0);
    WRITE(0);
    unsigned nb = (i1 - i0 + 63) >> 6;
    for (unsigned bi = 0; bi < nb; ++bi) {
      if (bi + 1 < nb) GATHER(i0 + (bi + 1) * 64);   // next batch in flight
      int n = (int)min(64u, i1 - i0 - bi * 64);
      int n4 = (n + 3) & ~3;                         // pad to group of 4 (nulls)
      const float4* __restrict__ L = lds[wv][bi & 1];
      for (int k = 0; k < n4; k += 4) {
        // 12 named loads first (ds_reads batch-issued), then 4 indep chains
        float4 a0 = L[(k+0)*3+0], a1 = L[(k+0)*3+1], a2 = L[(k+0)*3+2];
        float4 b0 = L[(k+1)*3+0], b1 = L[(k+1)*3+1], b2 = L[(k+1)*3+2];
        float4 c0 = L[(k+2)*3+0], c1 = L[(k+2)*3+1], c2 = L[(k+2)*3+2];
        float4 d0 = L[(k+3)*3+0], d1 = L[(k+3)*3+1], d2 = L[(k+3)*3+2];
        BODYG(a0, a1, a2, zmA, weA, lsA, bsA, flA);
        BODYG(b0, b1, b2, zmB, weB, lsB, bsB, flB);
        BODYG(c0, c1, c2, zmC, weC, lsC, bsC, flC);
        BODYG(d0, d1, d2, zmD, weD, lsD, bsD, flD);
      }
      if (bi + 1 < nb) WRITE((bi + 1) & 1);          // write after walk
    }
  }
  // merge the 4 partials with the k_final cross-chunk rules (NaN-safe)
  float zmin = INFINITY, weps = 0.f, lsum = 0.f;
  int best = 0;
  bool flag = false;
  auto MERGE = [&](float z, float e, float l, int bsx, bool flx) {
    flag |= flx;
    flag |= fabsf(z - zmin) < (e + weps + 2e-6f);
    if (z < zmin) { zmin = z; best = bsx; weps = e; }
    lsum += l;
  };
  MERGE(zmA, weA, lsA, bsA, flA);
  MERGE(zmB, weB, lsB, bsB, flB);
  MERGE(zmC, weC, lsC, bsC, flC);
  MERGE(zmD, weD, lsD, bsD, flD);
  int p = b * (HW * HW) + (y << 6) + x;
  unsigned pbv = (unsigned)best | (flag ? 0x80000000u : 0u);
  pc[(size_t)chunk * P + p] = make_float4(zmin, lsum, weps, __uint_as_float(pbv));
}

// exact f64 winner recompute + gather-interpolate + output write (not improb)
__device__ void write_winner(const float* __restrict__ vs_cam,
                             const int* __restrict__ faces,
                             const float* __restrict__ vnorm,
                             const float* __restrict__ attribs,
                             float* __restrict__ out, int P,
                             int b, int V, int F, int pix,
                             int best, bool covered) {
  int p = b * (HW * HW) + pix;
  float imn[3] = {0.f, 0.f, 0.f};
  float ima[3] = {0.f, 0.f, 0.f};
  if (covered) {
    int x = pix & 63, y = pix >> 6;
    const double step = 2.0 / 63.0;
    double px = (x == HW - 1) ? 1.0 : (x * step - 1.0);
    double py = (y == HW - 1) ? 1.0 : (y * step - 1.0);
    int vid[3] = {faces[best * 3 + 0], faces[best * 3 + 1], faces[best * 3 + 2]};
    const float* c0 = vs_cam + (size_t)(b * V + vid[0]) * 3;
    const float* c1 = vs_cam + (size_t)(b * V + vid[1]) * 3;
    const float* c2 = vs_cam + (size_t)(b * V + vid[2]) * 3;
    float v0x = c0[0] / c0[2], v0y = c0[1] / c0[2];
    float v1x = c1[0] / c1[2], v1y = c1[1] / c1[2];
    float v2x = c2[0] / c2[2], v2y = c2[1] / c2[2];
    float dx0 = v2x - v1x, dy0 = v2y - v1y;
    float dx1 = v0x - v2x, dy1 = v0y - v2y;
    float dx2 = v1x - v0x, dy2 = v1y - v0y;
    float A = dx2 * (v2y - v0y) - dy2 * (v2x - v0x);
    if (fabsf(A) < 1e-8f) A = 1e-8f;
    double invA = 1.0 / (double)A;
    double a0 = (double)dx0 * (py - (double)v1y) - (double)dy0 * (px - (double)v1x);
    double a1 = (double)dx1 * (py - (double)v2y) - (double)dy1 * (px - (double)v2x);
    double a2 = (double)dx2 * (py - (double)v0y) - (double)dy2 * (px - (double)v0x);
    double wk[3] = {a0 * invA, a1 * invA, a2 * invA};
    double v[6] = {0, 0, 0, 0, 0, 0};
#pragma unroll
    for (int k = 0; k < 3; ++k) {
      const float* n = vnorm + (size_t)(b * V + vid[k]) * 3;
      float nx = n[0], ny = n[1], nz = n[2];
      float nrm = sqrtf(nx * nx + ny * ny + nz * nz) + 1e-10f;  // f32, like ref
      const float* at = attribs + (((size_t)(b * F + best)) * 3 + k) * 3;
      v[0] += wk[k] * (double)(nx / nrm);
      v[1] += wk[k] * (double)(ny / nrm);
      v[2] += wk[k] * (double)(nz / nrm);
      v[3] += wk[k] * (double)at[0];
      v[4] += wk[k] * (double)at[1];
      v[5] += wk[k] * (double)at[2];
    }
    double nn = sqrt(v[0] * v[0] + v[1] * v[1] + v[2] * v[2]) + 1e-10;
    imn[0] = (float)(v[0] / nn);
    imn[1] = (float)(v[1] / nn);
    imn[2] = (float)(v[2] / nn);
    ima[0] = (float)v[3]; ima[1] = (float)v[4]; ima[2] = (float)v[5];
  }
  float* o_n = out;
  float* o_a = out + (size_t)P * 3;
  float* o_p = out + (size_t)P * 6;
  float* o_i = o_p + P;
  o_n[(size_t)p * 3 + 0] = imn[0];
  o_n[(size_t)p * 3 + 1] = imn[1];
  o_n[(size_t)p * 3 + 2] = imn[2];
  o_a[(size_t)p * 3 + 0] = ima[0];
  o_a[(size_t)p * 3 + 1] = ima[1];
  o_a[(size_t)p * 3 + 2] = ima[2];
  o_i[p] = covered ? (float)best : -1.0f;
}

__global__ void k_final(const float* __restrict__ vs_cam,
                        const int* __restrict__ faces,
                        const float* __restrict__ vnorm,
                        const float* __restrict__ attribs,
                        const float4* __restrict__ pc,
                        float* __restrict__ out,
                        int* __restrict__ cnt, int* __restrict__ list,
                        int B, int V, int F, int NC) {
  int p = blockIdx.x * blockDim.x + threadIdx.x;
  int P = B * HW * HW;
  if (p >= P) return;
  float zmin = INFINITY, weps = 0.f, lsum = 0.f;
  int best = 0;
  bool flag = false;
  for (int c = 0; c < NC; ++c) {
    float4 q = pc[(size_t)c * P + p];
    float z = q.x;
    float e = q.z;
    unsigned pb = __float_as_uint(q.w);
    flag |= (pb >> 31) != 0;
    flag |= fabsf(z - zmin) < (e + weps + 2e-6f);  // cross-chunk near-tie (NaN-safe)
    if (z < zmin) { zmin = z; best = (int)(pb & 0x7fffffffu); weps = e; }
    lsum += q.y;
  }
  bool covered = (zmin < 1e38f);
  int b = p >> 12;            // HW*HW = 4096
  int pix = p & 4095;
  write_winner(vs_cam, faces, vnorm, attribs, out, P, b, V, F, pix, best, covered);
  float* o_p = out + (size_t)P * 6;
  o_p[p] = 1.0f - __expf(lsum);
  if (flag) {
    int s = atomicAdd(cnt, 1);
    list[s] = p;
  }
}

// exact f64 re-argmin for flagged pixels: one wave per pixel.
// R13 lesson: the row-bucket walk thrashed L2 (rowbuk 6.1MB > 4MB/XCD; sparse
// 2-hop rl->record chains at HBM latency; FETCH 6.7GB, 160us). Fix: LINEAR
// streaming screen over frasF — iteration k reads 64 consecutive 64B records
// (perfectly coalesced, 1.5MB/image working set, L2-resident, independent
// iterations pipeline). Screen is sound: f64-exact inside => record-eval
// dmin >= -epsf (epsf bounds the f32 record eval error, by construction).
// Only ~0.5 faces/lane pass to the exact f64 path.
__global__ __launch_bounds__(256) void k_repair(
    const float* __restrict__ vs_cam,
    const int* __restrict__ faces,
    const float* __restrict__ vnorm,
    const float* __restrict__ attribs,
    const FaceRasF* __restrict__ frasF,
    const int* __restrict__ cnt, const int* __restrict__ list,
    float* __restrict__ out, int B, int V, int F) {
  int P = B * HW * HW;
  int gtid = blockIdx.x * blockDim.x + threadIdx.x;
  int wid = gtid >> 6;
  int lane = threadIdx.x & 63;
  int nwaves = (gridDim.x * blockDim.x) >> 6;
  int n = cnt[0];
  for (int i = wid; i < n; i += nwaves) {
    int p = list[i];
    int b = p >> 12;
    int pix = p & 4095;
    int x = pix & 63, y = pix >> 6;
    const double step = 2.0 / 63.0;
    double px = (x == HW - 1) ? 1.0 : (x * step - 1.0);
    double py = (y == HW - 1) ? 1.0 : (y * step - 1.0);
    float pxf = (float)px, pyf = (float)py;
    const float4* __restrict__ fb4 = (const float4*)(frasF + (size_t)b * F);
    double zmin = INFINITY;
    int best = 0x7fffffff;
    for (int f = lane; f < F; f += 64) {
      size_t o = (size_t)f * 4;
      float4 q0 = fb4[o + 0], q1 = fb4[o + 1], q2 = fb4[o + 2], q3 = fb4[o + 3];
      float w0f = fmaf(q0.x, pxf, fmaf(q0.y, pyf, q0.z));
      float w1f = fmaf(q0.w, pxf, fmaf(q1.x, pyf, q1.y));
      float w2f = fmaf(q1.z, pxf, fmaf(q1.w, pyf, q2.x));
      float dminf = fminf(fminf(w0f, w1f), w2f);
      if (dminf <= -q3.x) continue;          // sound screen: cannot be inside
      int i0 = faces[f * 3 + 0], i1 = faces[f * 3 + 1], i2 = faces[f * 3 + 2];
      const float* c0 = vs_cam + (size_t)(b * V + i0) * 3;
      const float* c1 = vs_cam + (size_t)(b * V + i1) * 3;
      const float* c2 = vs_cam + (size_t)(b * V + i2) * 3;
      float c0z = c0[2], c1z = c1[2], c2z = c2[2];
      float v0x = c0[0] / c0z, v0y = c0[1] / c0z;
      float v1x = c1[0] / c1z, v1y = c1[1] / c1z;
      float v2x = c2[0] / c2z, v2y = c2[1] / c2z;
      float dx0 = v2x - v1x, dy0 = v2y - v1y;
      float dx1 = v0x - v2x, dy1 = v0y - v2y;
      float dx2 = v1x - v0x, dy2 = v1y - v0y;
      float A = dx2 * (v2y - v0y) - dy2 * (v2x - v0x);
      if (fabsf(A) < 1e-8f) A = 1e-8f;
      double invA = 1.0 / (double)A;
      double a0 = (double)dx0 * (py - (double)v1y) - (double)dy0 * (px - (double)v1x);
      double a1 = (double)dx1 * (py - (double)v2y) - (double)dy1 * (px - (double)v2x);
      double a2 = (double)dx2 * (py - (double)v0y) - (double)dy2 * (px - (double)v0x);
      double w0 = a0 * invA, w1 = a1 * invA, w2 = a2 * invA;
      bool inside = (w0 >= 0.0) & (w1 >= 0.0) & (w2 >= 0.0);
      double z = (w0 * (double)c0z + w1 * (double)c1z) + w2 * (double)c2z;
      // in-lane lexicographic (z, idx): lanes visit ascending f, and the
      // cross-lane reduce below is (z, idx) too -> first-occurrence argmin
      if (inside & (z > 0.0) & ((z < zmin) | ((z == zmin) & (f < best)))) {
        zmin = z; best = f;
      }
    }
    // lexicographic (z, idx) wave reduce -> first-occurrence argmin
    for (int off = 32; off; off >>= 1) {
      double zo = __shfl_down(zmin, off);
      int bo = __shfl_down(best, off);
      if ((zo < zmin) || ((zo == zmin) && (bo < best))) { zmin = zo; best = bo; }
    }
    if (lane == 0) {
      bool covered = (zmin < 1e300);
      write_winner(vs_cam, faces, vnorm, attribs, out, P, b, V, F, pix, best, covered);
    }
  }
}

extern "C" void kernel_launch(void* const* d_in, const int* in_sizes, int n_in,
                              void* d_out, int out_size, void* d_ws, size_t ws_size,
                              hipStream_t stream) {
  const float* vert    = (const float*)d_in[0];
  const int*   faces   = (const int*)d_in[1];
  const float* attribs = (const float*)d_in[2];
  const float* rot     = (const float*)d_in[3];
  const float* trans   = (const float*)d_in[4];
  int B = in_sizes[4] / 3;
  int V = in_sizes[0] / (3 * B);
  int F = in_sizes[1] / 3;
  int P = B * HW * HW;
  int NR = B * HW;                              // total (b,row) buckets

  size_t CAP = (size_t)F;                       // exact worst case, no overflow
  size_t szFras  = sizeof(FaceRasF) * (size_t)B * F;
  size_t szBuk   = 4ull * (size_t)NR * CAP;
  size_t szVs    = 12ull * (size_t)B * V;
  size_t szVn    = 12ull * (size_t)B * V;
  size_t szRowC  = 4ull * (size_t)NR * CSTR;    // rowcnt (strided)
  size_t szCnt   = 4;
  size_t szPlist = 4ull * (size_t)P;
  size_t fixed   = szFras + szBuk + szVs + szVn + szRowC + szCnt + szPlist + 1024;

  int NC = 32;                                  // chunks
  while (NC > 2 && fixed + (size_t)P * 16ull * NC > ws_size) NC >>= 1;

  char* w = (char*)d_ws;
  FaceRasF* frasF  = (FaceRasF*)w; w += szFras;            // 64B-aligned
  float4* pc       = (float4*)w;   w += (size_t)P * 16ull * NC;
  unsigned* rowbuk = (unsigned*)w; w += szBuk;
  float* vs_cam    = (float*)w;    w += szVs;
  float* vnorm     = (float*)w;    w += szVn;
  unsigned* rowcnt = (unsigned*)w; w += szRowC;            // contiguous zero region:
  int* cnt         = (int*)w;      w += szCnt;             //   rowcnt + cnt
  int* list        = (int*)w;      /* P entries */
  int nzero = NR * CSTR + 1;

  k_prep<<<(B * V + 255) / 256, 256, 0, stream>>>(vert, rot, trans, vs_cam,
                                                  vnorm, rowcnt, nzero, B, V);
  dim3 fg((unsigned)((F + 255) / 256), (unsigned)B);
  k_facepre<<<fg, 256, 0, stream>>>(vs_cam, faces, frasF, vnorm, rowcnt,
                                    rowbuk, (unsigned)CAP, B, V, F);
  // 1-D chunk-fast grid: consecutive block IDs = chunks of the same pixgrp,
  // spread across CUs/XCDs; stride-16 rows inside blocks balance the rest.
  k_raster<<<(unsigned)(B * PPB * NC), 256, 0, stream>>>(frasF, rowcnt, rowbuk,
                                                         pc, (unsigned)CAP, F,
                                                         NC, P);
  k_final<<<(P + 255) / 256, 256, 0, stream>>>(vs_cam, faces, vnorm, attribs,
                                               pc, (float*)d_out, cnt, list,
                                               B, V, F, NC);
  k_repair<<<1024, 256, 0, stream>>>(vs_cam, faces, vnorm, attribs, frasF,
                                     cnt, list, (float*)d_out, B, V, F);
}

// Round 15
// 285.564 us; speedup vs baseline: 1.1215x; 1.0541x over previous
//
#include <hip/hip_runtime.h>
#include <math.h>

#define HW 64
#define PPB 16   // pixblocks per image: block q's 4 waves take rows q+16*wv
#define CSTR 8   // row-counter stride (words) to spread atomics across L2 channels

// f32 fast-raster record: 16 floats = 64 B
// float4 view: q0=(wx0,wy0,wc0,wx1) q1=(wy1,wc1,wx2,wy2) q2=(wc2,zx,zy,zc0) q3=(epsf,epsz,pad,pad)
// z is affine in screen coords: z(x,y) = zx*px + zy*py + zc0 (folded in f64).
struct FaceRasF {
  float wx0, wy0, wc0;
  float wx1, wy1, wc1;
  float wx2, wy2, wc2;
  float zx, zy, zc0;
  float epsf, epsz;
  float pad0, pad1;
};

// transform + ALL zero-init (vnorm, rowcnt, cnt): memset dispatch folded in.
__global__ void k_prep(const float* __restrict__ vert,
                       const float* __restrict__ rot,
                       const float* __restrict__ trans,
                       float* __restrict__ vs_cam,
                       float* __restrict__ vnorm,
                       unsigned* __restrict__ zerobase, int nzero,
                       int B, int V) {
  int i = blockIdx.x * blockDim.x + threadIdx.x;
  if (i < nzero) zerobase[i] = 0u;
  if (i >= B * V) return;
  int b = i / V;
  float x = vert[i * 3 + 0], y = vert[i * 3 + 1], z = vert[i * 3 + 2];
  const float* R = rot + b * 9;
  const float* t = trans + b * 3;
  vs_cam[i * 3 + 0] = ((x * R[0] + y * R[1]) + z * R[2]) + t[0];
  vs_cam[i * 3 + 1] = ((x * R[3] + y * R[4]) + z * R[5]) + t[1];
  vs_cam[i * 3 + 2] = ((x * R[6] + y * R[7]) + z * R[8]) + t[2];
  vnorm[i * 3 + 0] = 0.f;
  vnorm[i * 3 + 1] = 0.f;
  vnorm[i * 3 + 2] = 0.f;
}

// face precompute + DIRECT index-bucket emit (CAP=F exact worst case).
// grid: ((F+255)/256, B) so each wave has uniform b (ballot aggregation).
__global__ void k_facepre(const float* __restrict__ vs_cam,
                          const int* __restrict__ faces,
                          FaceRasF* __restrict__ frasF,
                          float* __restrict__ vnorm,
                          unsigned* __restrict__ rowcnt,
                          unsigned* __restrict__ rowbuk,
                          unsigned CAP, int B, int V, int F) {
  int f = blockIdx.x * blockDim.x + threadIdx.x;
  int b = blockIdx.y;
  bool valid = (f < F);
  int r0 = 1, r1 = 0;
  if (valid) {
    int i = b * F + f;
    int i0 = faces[f * 3 + 0], i1 = faces[f * 3 + 1], i2 = faces[f * 3 + 2];
    const float* c0 = vs_cam + (size_t)(b * V + i0) * 3;
    const float* c1 = vs_cam + (size_t)(b * V + i1) * 3;
    const float* c2 = vs_cam + (size_t)(b * V + i2) * 3;
    float c0x = c0[0], c0y = c0[1], c0z = c0[2];
    float c1x = c1[0], c1y = c1[1], c1z = c1[2];
    float c2x = c2[0], c2y = c2[1], c2z = c2[2];
    float v0x = c0x / c0z, v0y = c0y / c0z;
    float v1x = c1x / c1z, v1y = c1y / c1z;
    float v2x = c2x / c2z, v2y = c2y / c2z;
    float dx0 = v2x - v1x, dy0 = v2y - v1y;   // edge(v1,v2), anchor v1
    float dx1 = v0x - v2x, dy1 = v0y - v2y;   // edge(v2,v0), anchor v2
    float dx2 = v1x - v0x, dy2 = v1y - v0y;   // edge(v0,v1), anchor v0
    float Araw = dx2 * (v2y - v0y) - dy2 * (v2x - v0x);
    float A = (fabsf(Araw) < 1e-8f) ? 1e-8f : Araw;
    double invA = 1.0 / (double)A;
    double wx0 = -(double)dy0 * invA, wy0 = (double)dx0 * invA;
    double wc0 = ((double)dy0 * (double)v1x - (double)dx0 * (double)v1y) * invA;
    double wx1 = -(double)dy1 * invA, wy1 = (double)dx1 * invA;
    double wc1 = ((double)dy1 * (double)v2x - (double)dx1 * (double)v2y) * invA;
    double wx2 = -(double)dy2 * invA, wy2 = (double)dx2 * invA;
    double wc2 = ((double)dy2 * (double)v0x - (double)dx2 * (double)v0y) * invA;
    double m0 = fabs(wx0) + fabs(wy0) + fabs(wc0);
    double m1 = fabs(wx1) + fabs(wy1) + fabs(wc1);
    double m2 = fabs(wx2) + fabs(wy2) + fabs(wc2);
    double mm = fmax(fmax(m0, m1), m2);
    float epsf = fmaxf((float)(6e-7 * mm), 3e-7f);
    float zs = fabsf(c0z) + fabsf(c1z) + fabsf(c2z);
    // budget: w-eval error (epsf) + affine-z fold error (<=3 f32 roundings)
    float epsz = (2.0f * epsf + 4e-6f) * zs;
    // z-plane coefficients in f64: z(x,y) = zx*px + zy*py + zc0
    double zxd = wx0 * (double)c0z + wx1 * (double)c1z + wx2 * (double)c2z;
    double zyd = wy0 * (double)c0z + wy1 * (double)c1z + wy2 * (double)c2z;
    double zcd = wc0 * (double)c0z + wc1 * (double)c1z + wc2 * (double)c2z;
    FaceRasF fr;
    fr.wx0 = (float)wx0; fr.wy0 = (float)wy0; fr.wc0 = (float)wc0;
    fr.wx1 = (float)wx1; fr.wy1 = (float)wy1; fr.wc1 = (float)wc1;
    fr.wx2 = (float)wx2; fr.wy2 = (float)wy2; fr.wc2 = (float)wc2;
    fr.zx = (float)zxd; fr.zy = (float)zyd; fr.zc0 = (float)zcd;
    fr.epsf = epsf; fr.epsz = epsz; fr.pad0 = 0.f; fr.pad1 = 0.f;
    frasF[i] = fr;
    // EXACT y-range of {dmin >= -band} via the barycentric slab:
    // w0+w1+w2 == 1, so dmin>=-b <=> all w_i>=-b, and y = sum w_i*v_iy over that
    // slab has exact extremes vext + b*(3*vext - sum).
    float band = fmaxf(0.202f, 1.6f * epsf);
    if (fabsf(Araw) < 1e-8f) {
      r0 = 0; r1 = 63;            // degenerate clamp: sum(w) != 1, no bound
    } else {
      float vmin = fminf(v0y, fminf(v1y, v2y));
      float vmax = fmaxf(v0y, fmaxf(v1y, v2y));
      float s3 = v0y + v1y + v2y;
      float b1 = band * 1.05f + 1e-4f;        // slack for f32 rounding
      float ylo = vmin + b1 * (3.f * vmin - s3);
      float yhi = vmax + b1 * (3.f * vmax - s3);
      if (yhi < -1.001f || ylo > 1.001f) { r0 = 1; r1 = 0; }
      else {
        r0 = max(0, (int)floorf((ylo + 1.0f) * 31.5f) - 1);
        r1 = min(63, (int)ceilf((yhi + 1.0f) * 31.5f) + 1);
        if (r0 > r1) { r0 = 1; r1 = 0; }
      }
    }
    // face normal -> vertex normal scatter (f32 atomics, fire-and-forget)
    float e1x = c1x - c0x, e1y = c1y - c0y, e1z = c1z - c0z;
    float e2x = c2x - c0x, e2y = c2y - c0y, e2z = c2z - c0z;
    float nx = e1y * e2z - e1z * e2y;
    float ny = e1z * e2x - e1x * e2z;
    float nz = e1x * e2y - e1y * e2x;
    float* vn0 = vnorm + (size_t)(b * V + i0) * 3;
    float* vn1 = vnorm + (size_t)(b * V + i1) * 3;
    float* vn2 = vnorm + (size_t)(b * V + i2) * 3;
    atomicAdd(vn0 + 0, nx); atomicAdd(vn0 + 1, ny); atomicAdd(vn0 + 2, nz);
    atomicAdd(vn1 + 0, nx); atomicAdd(vn1 + 1, ny); atomicAdd(vn1 + 2, nz);
    atomicAdd(vn2 + 0, nx); atomicAdd(vn2 + 1, ny); atomicAdd(vn2 + 2, nz);
  }
  // wave-aggregated bucket append, trimmed to the wave's row union
  int lane = threadIdx.x & 63;
  bool has = valid && r0 <= r1;
  int rmin = has ? r0 : 64, rmax = has ? r1 : -1;
  for (int off = 32; off; off >>= 1) {
    rmin = min(rmin, __shfl_xor(rmin, off));
    rmax = max(rmax, __shfl_xor(rmax, off));
  }
  for (int r = rmin; r <= rmax; ++r) {
    bool in = has && r >= r0 && r <= r1;
    unsigned long long m = __ballot(in);
    if (m == 0ull) continue;
    int row = (b << 6) | r;
    int leader = __ffsll(m) - 1;
    unsigned base = 0;
    if (lane == leader) base = atomicAdd(&rowcnt[row * CSTR], (unsigned)__popcll(m));
    base = (unsigned)__shfl((int)base, leader);
    if (in) {
      unsigned pos = base + (unsigned)__popcll(m & ((1ull << lane) - 1ull));
      rowbuk[(size_t)row * CAP + pos] = (unsigned)f;   // pos < F == CAP always
    }
  }
}

// f32 screened raster: LDS-staged batches + 4 independent accumulator sets;
// stride-16 row assignment + 1-D chunk-fast grid (R12: fixed the CU-queueing
// hotspot that was the R2-R11 ~100us invariant).
__global__ __launch_bounds__(256) void k_raster(
    const FaceRasF* __restrict__ frasF,
    const unsigned* __restrict__ rowcnt,
    const unsigned* __restrict__ rowbuk,
    float4* __restrict__ pc,
    unsigned CAP, int F, int NC, int P) {
  __shared__ float4 lds[4][2][64 * 3];   // [wave][buf][entry*3] = 24 KB
  int bid = blockIdx.x;
  int chunk = bid % NC;                  // chunk-fast: consecutive IDs spread
  int g = bid / NC;
  int b = g / PPB;
  int q = g % PPB;
  int wv = threadIdx.x >> 6;
  int lane = threadIdx.x & 63;
  int y = q + 16 * wv;                   // stride-16 rows: block-level balance
  int x = lane;
  const double step = 2.0 / 63.0;
  double pxd = (x == HW - 1) ? 1.0 : (x * step - 1.0);
  double pyd = (y == HW - 1) ? 1.0 : (y * step - 1.0);
  float pxf = (float)pxd, pyf = (float)pyd;

  // 4 independent accumulator sets (named: rule #20)
  float zmA = INFINITY, zmB = INFINITY, zmC = INFINITY, zmD = INFINITY;
  float weA = 0.f, weB = 0.f, weC = 0.f, weD = 0.f;
  float lsA = 0.f, lsB = 0.f, lsC = 0.f, lsD = 0.f;
  int bsA = 0, bsB = 0, bsC = 0, bsD = 0;
  bool flA = false, flB = false, flC = false, flD = false;

  auto BODYG = [&](float4 r0, float4 r1, float4 r2,
                   float& zm, float& we, float& ls, int& bs, bool& fl) {
    float w0 = fmaf(r0.x, pxf, r0.w);   // == fmaf(wx,px,fmaf(wy,py,wc))
    float w1 = fmaf(r0.y, pxf, r1.x);
    float w2 = fmaf(r0.z, pxf, r1.y);
    float dmin = fminf(fminf(w0, w1), w2);
    float t = fminf(fmaxf(dmin * 100.0f, -30.0f), 0.0f);
    float pr = __expf(t);               // inside -> t=0 -> pr=1 exactly
    float lg = __logf(fmaf(-pr, 0.99999990f, 1.0f));
    ls += (dmin > -0.2f) ? lg : 0.0f;   // dmin<=-0.2 contributes <=2e-9
    float z = fmaf(r1.z, pxf, r1.w);    // z affine: zx*px + zc
    float ef = r2.x, ez = r2.y;
    bool act = dmin > -ef;
    bool ge0 = dmin >= 0.0f;
    bool contend = (z < zm + ez + we) & (z > -ez);
    fl |= act & (fabsf(dmin) < ef) & contend;          // inside-sign ambiguous
    fl |= act & ge0 & (fabsf(z) < ez);                 // z>0 boundary ambiguous
    fl |= act & ge0 & (z > 0.0f) & (fabsf(z - zm) < ez + we); // z-order ambig.
    bool take = act & ge0 & (z > 0.0f) & (z < zm);     // ties repaired in f64
    zm = take ? z : zm;
    bs = take ? __float_as_int(r2.z) : bs;
    we = take ? ez : we;
  };

  int row = (b << 6) | y;                      // wave-uniform: wave = one row
  unsigned fill = rowcnt[row * CSTR];
  const unsigned* __restrict__ rl = rowbuk + (size_t)row * CAP;
  const float4* __restrict__ fb4 = (const float4*)(frasF + (size_t)b * F);
  unsigned per = (fill + (unsigned)NC - 1) / (unsigned)NC;
  unsigned i0 = min(fill, (unsigned)chunk * per);
  unsigned i1 = min(fill, i0 + per);
  if (i0 < i1) {
    // lane-parallel gather (per-lane vector loads, vmcnt-counted): 64 records
    // in ONE memory latency; issued EARLY, LDS-written LATE. OOR lanes -> null.
    float4 g0, g1, g2;
    auto GATHER = [&](unsigned base) {
      unsigned j = base + (unsigned)lane;
      bool ok = (j < i1);
      unsigned jj = ok ? j : (i1 - 1);
      int fidx = (int)rl[jj];
      size_t o = (size_t)fidx * 4;
      float4 q0 = fb4[o + 0], q1 = fb4[o + 1], q2 = fb4[o + 2], q3 = fb4[o + 3];
      float ce0 = fmaf(q0.y, pyf, q0.z);     // wy*py+wc (py wave-uniform)
      float ce1 = fmaf(q1.x, pyf, q1.y);
      float ce2 = fmaf(q1.w, pyf, q2.x);
      float zc  = fmaf(q2.z, pyf, q2.w);     // zy*py+zc0
      // null record for OOR: ce0=-1e30 -> dmin=-1e30 -> all gates false
      g0 = make_float4(ok ? q0.x : 0.f, ok ? q0.w : 0.f, ok ? q1.z : 0.f,
                       ok ? ce0 : -1e30f);
      g1 = make_float4(ok ? ce1 : 0.f, ok ? ce2 : 0.f, ok ? q2.y : 0.f,
                       ok ? zc : 0.f);
      g2 = make_float4(ok ? q3.x : 0.f, ok ? q3.y : 0.f,
                       __int_as_float(ok ? fidx : 0), 0.f);
    };
    auto WRITE = [&](int buf) {
      lds[wv][buf][lane * 3 + 0] = g0;
      lds[wv][buf][lane * 3 + 1] = g1;
      lds[wv][buf][lane * 3 + 2] = g2;
    };
    GATHER(i0);
    WRITE(0);
    unsigned nb = (i1 - i0 + 63) >> 6;
    for (unsigned bi = 0; bi < nb; ++bi) {
      if (bi + 1 < nb) GATHER(i0 + (bi + 1) * 64);   // next batch in flight
      int n = (int)min(64u, i1 - i0 - bi * 64);
      int n4 = (n + 3) & ~3;                         // pad to group of 4 (nulls)
      const float4* __restrict__ L = lds[wv][bi & 1];
      for (int k = 0; k < n4; k += 4) {
        // 12 named loads first (ds_reads batch-issued), then 4 indep chains
        float4 a0 = L[(k+0)*3+0], a1 = L[(k+0)*3+1], a2 = L[(k+0)*3+2];
        float4 b0 = L[(k+1)*3+0], b1 = L[(k+1)*3+1], b2 = L[(k+1)*3+2];
        float4 c0 = L[(k+2)*3+0], c1 = L[(k+2)*3+1], c2 = L[(k+2)*3+2];
        float4 d0 = L[(k+3)*3+0], d1 = L[(k+3)*3+1], d2 = L[(k+3)*3+2];
        BODYG(a0, a1, a2, zmA, weA, lsA, bsA, flA);
        BODYG(b0, b1, b2, zmB, weB, lsB, bsB, flB);
        BODYG(c0, c1, c2, zmC, weC, lsC, bsC, flC);
        BODYG(d0, d1, d2, zmD, weD, lsD, bsD, flD);
      }
      if (bi + 1 < nb) WRITE((bi + 1) & 1);          // write after walk
    }
  }
  // merge the 4 partials with the k_final cross-chunk rules (NaN-safe)
  float zmin = INFINITY, weps = 0.f, lsum = 0.f;
  int best = 0;
  bool flag = false;
  auto MERGE = [&](float z, float e, float l, int bsx, bool flx) {
    flag |= flx;
    flag |= fabsf(z - zmin) < (e + weps + 2e-6f);
    if (z < zmin) { zmin = z; best = bsx; weps = e; }
    lsum += l;
  };
  MERGE(zmA, weA, lsA, bsA, flA);
  MERGE(zmB, weB, lsB, bsB, flB);
  MERGE(zmC, weC, lsC, bsC, flC);
  MERGE(zmD, weD, lsD, bsD, flD);
  int p = b * (HW * HW) + (y << 6) + x;
  unsigned pbv = (unsigned)best | (flag ? 0x80000000u : 0u);
  pc[(size_t)chunk * P + p] = make_float4(zmin, lsum, weps, __uint_as_float(pbv));
}

// exact f64 winner recompute + gather-interpolate + output write (not improb)
__device__ void write_winner(const float* __restrict__ vs_cam,
                             const int* __restrict__ faces,
                             const float* __restrict__ vnorm,
                             const float* __restrict__ attribs,
                             float* __restrict__ out, int P,
                             int b, int V, int F, int pix,
                             int best, bool covered) {
  int p = b * (HW * HW) + pix;
  float imn[3] = {0.f, 0.f, 0.f};
  float ima[3] = {0.f, 0.f, 0.f};
  if (covered) {
    int x = pix & 63, y = pix >> 6;
    const double step = 2.0 / 63.0;
    double px = (x == HW - 1) ? 1.0 : (x * step - 1.0);
    double py = (y == HW - 1) ? 1.0 : (y * step - 1.0);
    int vid[3] = {faces[best * 3 + 0], faces[best * 3 + 1], faces[best * 3 + 2]};
    const float* c0 = vs_cam + (size_t)(b * V + vid[0]) * 3;
    const float* c1 = vs_cam + (size_t)(b * V + vid[1]) * 3;
    const float* c2 = vs_cam + (size_t)(b * V + vid[2]) * 3;
    float v0x = c0[0] / c0[2], v0y = c0[1] / c0[2];
    float v1x = c1[0] / c1[2], v1y = c1[1] / c1[2];
    float v2x = c2[0] / c2[2], v2y = c2[1] / c2[2];
    float dx0 = v2x - v1x, dy0 = v2y - v1y;
    float dx1 = v0x - v2x, dy1 = v0y - v2y;
    float dx2 = v1x - v0x, dy2 = v1y - v0y;
    float A = dx2 * (v2y - v0y) - dy2 * (v2x - v0x);
    if (fabsf(A) < 1e-8f) A = 1e-8f;
    double invA = 1.0 / (double)A;
    double a0 = (double)dx0 * (py - (double)v1y) - (double)dy0 * (px - (double)v1x);
    double a1 = (double)dx1 * (py - (double)v2y) - (double)dy1 * (px - (double)v2x);
    double a2 = (double)dx2 * (py - (double)v0y) - (double)dy2 * (px - (double)v0x);
    double wk[3] = {a0 * invA, a1 * invA, a2 * invA};
    double v[6] = {0, 0, 0, 0, 0, 0};
#pragma unroll
    for (int k = 0; k < 3; ++k) {
      const float* n = vnorm + (size_t)(b * V + vid[k]) * 3;
      float nx = n[0], ny = n[1], nz = n[2];
      float nrm = sqrtf(nx * nx + ny * ny + nz * nz) + 1e-10f;  // f32, like ref
      const float* at = attribs + (((size_t)(b * F + best)) * 3 + k) * 3;
      v[0] += wk[k] * (double)(nx / nrm);
      v[1] += wk[k] * (double)(ny / nrm);
      v[2] += wk[k] * (double)(nz / nrm);
      v[3] += wk[k] * (double)at[0];
      v[4] += wk[k] * (double)at[1];
      v[5] += wk[k] * (double)at[2];
    }
    double nn = sqrt(v[0] * v[0] + v[1] * v[1] + v[2] * v[2]) + 1e-10;
    imn[0] = (float)(v[0] / nn);
    imn[1] = (float)(v[1] / nn);
    imn[2] = (float)(v[2] / nn);
    ima[0] = (float)v[3]; ima[1] = (float)v[4]; ima[2] = (float)v[5];
  }
  float* o_n = out;
  float* o_a = out + (size_t)P * 3;
  float* o_p = out + (size_t)P * 6;
  float* o_i = o_p + P;
  o_n[(size_t)p * 3 + 0] = imn[0];
  o_n[(size_t)p * 3 + 1] = imn[1];
  o_n[(size_t)p * 3 + 2] = imn[2];
  o_a[(size_t)p * 3 + 0] = ima[0];
  o_a[(size_t)p * 3 + 1] = ima[1];
  o_a[(size_t)p * 3 + 2] = ima[2];
  o_i[p] = covered ? (float)best : -1.0f;
}

__global__ void k_final(const float* __restrict__ vs_cam,
                        const int* __restrict__ faces,
                        const float* __restrict__ vnorm,
                        const float* __restrict__ attribs,
                        const float4* __restrict__ pc,
                        float* __restrict__ out,
                        int* __restrict__ cnt, int* __restrict__ list,
                        int B, int V, int F, int NC) {
  int p = blockIdx.x * blockDim.x + threadIdx.x;
  int P = B * HW * HW;
  if (p >= P) return;
  float zmin = INFINITY, weps = 0.f, lsum = 0.f;
  int best = 0;
  bool flag = false;
  for (int c = 0; c < NC; ++c) {
    float4 q = pc[(size_t)c * P + p];
    float z = q.x;
    float e = q.z;
    unsigned pb = __float_as_uint(q.w);
    flag |= (pb >> 31) != 0;
    flag |= fabsf(z - zmin) < (e + weps + 2e-6f);  // cross-chunk near-tie (NaN-safe)
    if (z < zmin) { zmin = z; best = (int)(pb & 0x7fffffffu); weps = e; }
    lsum += q.y;
  }
  bool covered = (zmin < 1e38f);
  int b = p >> 12;            // HW*HW = 4096
  int pix = p & 4095;
  write_winner(vs_cam, faces, vnorm, attribs, out, P, b, V, F, pix, best, covered);
  float* o_p = out + (size_t)P * 6;
  o_p[p] = 1.0f - __expf(lsum);
  if (flag) {
    int s = atomicAdd(cnt, 1);
    list[s] = p;
  }
}

// exact f64 re-argmin for flagged pixels: one wave per pixel, TWO PHASES.
// R12-R14 data (units-corrected: FETCH was MB, caches absorb everything):
// branchless full-f64 walk = 71us; walks with an early-`continue` screen =
// 149-160us. The branch fenced cross-iteration pipelining (R4/R6 lesson).
// Phase 1: BRANCH-FREE streaming screen over frasF (coalesced, affine) with
// ballot/prefix compaction of passing faces into LDS (select-slotted store,
// no divergent branch; only the scalar count carries across iterations).
// Screen sound: f64-inside => record dmin >= -epsf (epsf's defining bound).
// Phase 2: ~8 survivors distributed one-per-lane -> their dependent
// faces->vs_cam->f64 chains run CONCURRENTLY; (z,f)-lex reduce preserves
// first-occurrence argmin (compaction keeps ascending f order).
__global__ __launch_bounds__(256) void k_repair(
    const float* __restrict__ vs_cam,
    const int* __restrict__ faces,
    const float* __restrict__ vnorm,
    const float* __restrict__ attribs,
    const FaceRasF* __restrict__ frasF,
    const int* __restrict__ cnt, const int* __restrict__ list,
    float* __restrict__ out, int B, int V, int F) {
  __shared__ unsigned plist[4][320];   // [wave][256 real + 64 scratch slots]
  int P = B * HW * HW;
  int gtid = blockIdx.x * blockDim.x + threadIdx.x;
  int wid = gtid >> 6;
  int wv = (threadIdx.x >> 6) & 3;
  int lane = threadIdx.x & 63;
  int nwaves = (gridDim.x * blockDim.x) >> 6;
  int n = cnt[0];
  for (int i = wid; i < n; i += nwaves) {
    int p = list[i];
    int b = p >> 12;
    int pix = p & 4095;
    int x = pix & 63, y = pix >> 6;
    const double step = 2.0 / 63.0;
    double px = (x == HW - 1) ? 1.0 : (x * step - 1.0);
    double py = (y == HW - 1) ? 1.0 : (y * step - 1.0);
    float pxf = (float)px, pyf = (float)py;
    const float4* __restrict__ fb4 = (const float4*)(frasF + (size_t)b * F);
    // ---- phase 1: branch-free screen + LDS compaction
    unsigned nf = 0;
    bool ovf = false;
    for (int f0 = 0; f0 < F; f0 += 64) {
      int fc = min(f0 + lane, F - 1);
      size_t o = (size_t)fc * 4;
      float4 q0 = fb4[o + 0], q1 = fb4[o + 1], q2 = fb4[o + 2], q3 = fb4[o + 3];
      float w0f = fmaf(q0.x, pxf, fmaf(q0.y, pyf, q0.z));
      float w1f = fmaf(q0.w, pxf, fmaf(q1.x, pyf, q1.y));
      float w2f = fmaf(q1.z, pxf, fmaf(q1.w, pyf, q2.x));
      float dminf = fminf(fminf(w0f, w1f), w2f);
      bool pass = (dminf > -q3.x) & (f0 + lane < F);
      unsigned long long m = __ballot(pass);
      unsigned pos = nf + (unsigned)__popcll(m & ((1ull << lane) - 1ull));
      bool ok = pass & (pos < 256u);
      unsigned slot = ok ? pos : (256u + (unsigned)lane);  // scratch: no branch
      plist[wv][slot] = (unsigned)(f0 + lane);
      unsigned c = (unsigned)__popcll(m);
      ovf |= (nf + c > 256u);
      nf += c;
    }
    // ---- phase 2: parallel exact f64 over survivors (ascending-f order kept)
    double zmin = INFINITY;
    int best = 0x7fffffff;
    unsigned n2 = ovf ? (unsigned)F : min(nf, 256u);
    for (unsigned j = lane; j < n2; j += 64) {
      int f = ovf ? (int)j : (int)plist[wv][j];   // fallback: all faces (rare)
      int i0 = faces[f * 3 + 0], i1 = faces[f * 3 + 1], i2 = faces[f * 3 + 2];
      const float* c0 = vs_cam + (size_t)(b * V + i0) * 3;
      const float* c1 = vs_cam + (size_t)(b * V + i1) * 3;
      const float* c2 = vs_cam + (size_t)(b * V + i2) * 3;
      float c0z = c0[2], c1z = c1[2], c2z = c2[2];
      float v0x = c0[0] / c0z, v0y = c0[1] / c0z;
      float v1x = c1[0] / c1z, v1y = c1[1] / c1z;
      float v2x = c2[0] / c2z, v2y = c2[1] / c2z;
      float dx0 = v2x - v1x, dy0 = v2y - v1y;
      float dx1 = v0x - v2x, dy1 = v0y - v2y;
      float dx2 = v1x - v0x, dy2 = v1y - v0y;
      float A = dx2 * (v2y - v0y) - dy2 * (v2x - v0x);
      if (fabsf(A) < 1e-8f) A = 1e-8f;
      double invA = 1.0 / (double)A;
      double a0 = (double)dx0 * (py - (double)v1y) - (double)dy0 * (px - (double)v1x);
      double a1 = (double)dx1 * (py - (double)v2y) - (double)dy1 * (px - (double)v2x);
      double a2 = (double)dx2 * (py - (double)v0y) - (double)dy2 * (px - (double)v0x);
      double w0 = a0 * invA, w1 = a1 * invA, w2 = a2 * invA;
      bool inside = (w0 >= 0.0) & (w1 >= 0.0) & (w2 >= 0.0);
      double z = (w0 * (double)c0z + w1 * (double)c1z) + w2 * (double)c2z;
      // in-lane lexicographic (z, idx): entries ascend in f per lane
      if (inside & (z > 0.0) & ((z < zmin) | ((z == zmin) & (f < best)))) {
        zmin = z; best = f;
      }
    }
    // lexicographic (z, idx) wave reduce -> first-occurrence argmin
    for (int off = 32; off; off >>= 1) {
      double zo = __shfl_down(zmin, off);
      int bo = __shfl_down(best, off);
      if ((zo < zmin) || ((zo == zmin) && (bo < best))) { zmin = zo; best = bo; }
    }
    if (lane == 0) {
      bool covered = (zmin < 1e300);
      write_winner(vs_cam, faces, vnorm, attribs, out, P, b, V, F, pix, best, covered);
    }
  }
}

extern "C" void kernel_launch(void* const* d_in, const int* in_sizes, int n_in,
                              void* d_out, int out_size, void* d_ws, size_t ws_size,
                              hipStream_t stream) {
  const float* vert    = (const float*)d_in[0];
  const int*   faces   = (const int*)d_in[1];
  const float* attribs = (const float*)d_in[2];
  const float* rot     = (const float*)d_in[3];
  const float* trans   = (const float*)d_in[4];
  int B = in_sizes[4] / 3;
  int V = in_sizes[0] / (3 * B);
  int F = in_sizes[1] / 3;
  int P = B * HW * HW;
  int NR = B * HW;                              // total (b,row) buckets

  size_t CAP = (size_t)F;                       // exact worst case, no overflow
  size_t szFras  = sizeof(FaceRasF) * (size_t)B * F;
  size_t szBuk   = 4ull * (size_t)NR * CAP;
  size_t szVs    = 12ull * (size_t)B * V;
  size_t szVn    = 12ull * (size_t)B * V;
  size_t szRowC  = 4ull * (size_t)NR * CSTR;    // rowcnt (strided)
  size_t szCnt   = 4;
  size_t szPlist = 4ull * (size_t)P;
  size_t fixed   = szFras + szBuk + szVs + szVn + szRowC + szCnt + szPlist + 1024;

  int NC = 32;                                  // chunks
  while (NC > 2 && fixed + (size_t)P * 16ull * NC > ws_size) NC >>= 1;

  char* w = (char*)d_ws;
  FaceRasF* frasF  = (FaceRasF*)w; w += szFras;            // 64B-aligned
  float4* pc       = (float4*)w;   w += (size_t)P * 16ull * NC;
  unsigned* rowbuk = (unsigned*)w; w += szBuk;
  float* vs_cam    = (float*)w;    w += szVs;
  float* vnorm     = (float*)w;    w += szVn;
  unsigned* rowcnt = (unsigned*)w; w += szRowC;            // contiguous zero region:
  int* cnt         = (int*)w;      w += szCnt;             //   rowcnt + cnt
  int* list        = (int*)w;      /* P entries */
  int nzero = NR * CSTR + 1;

  k_prep<<<(B * V + 255) / 256, 256, 0, stream>>>(vert, rot, trans, vs_cam,
                                                  vnorm, rowcnt, nzero, B, V);
  dim3 fg((unsigned)((F + 255) / 256), (unsigned)B);
  k_facepre<<<fg, 256, 0, stream>>>(vs_cam, faces, frasF, vnorm, rowcnt,
                                    rowbuk, (unsigned)CAP, B, V, F);
  // 1-D chunk-fast grid: consecutive block IDs = chunks of the same pixgrp,
  // spread across CUs/XCDs; stride-16 rows inside blocks balance the rest.
  k_raster<<<(unsigned)(B * PPB * NC), 256, 0, stream>>>(frasF, rowcnt, rowbuk,
                                                         pc, (unsigned)CAP, F,
                                                         NC, P);
  k_final<<<(P + 255) / 256, 256, 0, stream>>>(vs_cam, faces, vnorm, attribs,
                                               pc, (float*)d_out, cnt, list,
                                               B, V, F, NC);
  k_repair<<<1024, 256, 0, stream>>>(vs_cam, faces, vnorm, attribs, frasF,
                                     cnt, list, (float*)d_out, B, V, F);
}

// Round 16
// 199.898 us; speedup vs baseline: 1.6020x; 1.4285x over previous
//
#include <hip/hip_runtime.h>
#include <math.h>

#define HW 64
#define PPB 16   // pixblocks per image: block q's 4 waves take rows q+16*wv
#define CSTR 8   // row-counter stride (words) to spread atomics across L2 channels

// f32 fast-raster record: 16 floats = 64 B
// float4 view: q0=(wx0,wy0,wc0,wx1) q1=(wy1,wc1,wx2,wy2) q2=(wc2,zx,zy,zc0) q3=(epsf,epsz,pad,pad)
// z is affine in screen coords: z(x,y) = zx*px + zy*py + zc0 (folded in f64).
struct FaceRasF {
  float wx0, wy0, wc0;
  float wx1, wy1, wc1;
  float wx2, wy2, wc2;
  float zx, zy, zc0;
  float epsf, epsz;
  float pad0, pad1;
};

// transform + ALL zero-init (vnorm, rowcnt, cnt): memset dispatch folded in.
__global__ void k_prep(const float* __restrict__ vert,
                       const float* __restrict__ rot,
                       const float* __restrict__ trans,
                       float* __restrict__ vs_cam,
                       float* __restrict__ vnorm,
                       unsigned* __restrict__ zerobase, int nzero,
                       int B, int V) {
  int i = blockIdx.x * blockDim.x + threadIdx.x;
  if (i < nzero) zerobase[i] = 0u;
  if (i >= B * V) return;
  int b = i / V;
  float x = vert[i * 3 + 0], y = vert[i * 3 + 1], z = vert[i * 3 + 2];
  const float* R = rot + b * 9;
  const float* t = trans + b * 3;
  vs_cam[i * 3 + 0] = ((x * R[0] + y * R[1]) + z * R[2]) + t[0];
  vs_cam[i * 3 + 1] = ((x * R[3] + y * R[4]) + z * R[5]) + t[1];
  vs_cam[i * 3 + 2] = ((x * R[6] + y * R[7]) + z * R[8]) + t[2];
  vnorm[i * 3 + 0] = 0.f;
  vnorm[i * 3 + 1] = 0.f;
  vnorm[i * 3 + 2] = 0.f;
}

// face precompute + DIRECT index-bucket emit (CAP=F exact worst case).
// grid: ((F+255)/256, B) so each wave has uniform b (ballot aggregation).
__global__ void k_facepre(const float* __restrict__ vs_cam,
                          const int* __restrict__ faces,
                          FaceRasF* __restrict__ frasF,
                          float* __restrict__ vnorm,
                          unsigned* __restrict__ rowcnt,
                          unsigned* __restrict__ rowbuk,
                          unsigned CAP, int B, int V, int F) {
  int f = blockIdx.x * blockDim.x + threadIdx.x;
  int b = blockIdx.y;
  bool valid = (f < F);
  int r0 = 1, r1 = 0;
  if (valid) {
    int i = b * F + f;
    int i0 = faces[f * 3 + 0], i1 = faces[f * 3 + 1], i2 = faces[f * 3 + 2];
    const float* c0 = vs_cam + (size_t)(b * V + i0) * 3;
    const float* c1 = vs_cam + (size_t)(b * V + i1) * 3;
    const float* c2 = vs_cam + (size_t)(b * V + i2) * 3;
    float c0x = c0[0], c0y = c0[1], c0z = c0[2];
    float c1x = c1[0], c1y = c1[1], c1z = c1[2];
    float c2x = c2[0], c2y = c2[1], c2z = c2[2];
    float v0x = c0x / c0z, v0y = c0y / c0z;
    float v1x = c1x / c1z, v1y = c1y / c1z;
    float v2x = c2x / c2z, v2y = c2y / c2z;
    float dx0 = v2x - v1x, dy0 = v2y - v1y;   // edge(v1,v2), anchor v1
    float dx1 = v0x - v2x, dy1 = v0y - v2y;   // edge(v2,v0), anchor v2
    float dx2 = v1x - v0x, dy2 = v1y - v0y;   // edge(v0,v1), anchor v0
    float Araw = dx2 * (v2y - v0y) - dy2 * (v2x - v0x);
    float A = (fabsf(Araw) < 1e-8f) ? 1e-8f : Araw;
    double invA = 1.0 / (double)A;
    double wx0 = -(double)dy0 * invA, wy0 = (double)dx0 * invA;
    double wc0 = ((double)dy0 * (double)v1x - (double)dx0 * (double)v1y) * invA;
    double wx1 = -(double)dy1 * invA, wy1 = (double)dx1 * invA;
    double wc1 = ((double)dy1 * (double)v2x - (double)dx1 * (double)v2y) * invA;
    double wx2 = -(double)dy2 * invA, wy2 = (double)dx2 * invA;
    double wc2 = ((double)dy2 * (double)v0x - (double)dx2 * (double)v0y) * invA;
    double m0 = fabs(wx0) + fabs(wy0) + fabs(wc0);
    double m1 = fabs(wx1) + fabs(wy1) + fabs(wc1);
    double m2 = fabs(wx2) + fabs(wy2) + fabs(wc2);
    double mm = fmax(fmax(m0, m1), m2);
    float epsf = fmaxf((float)(6e-7 * mm), 3e-7f);
    float zs = fabsf(c0z) + fabsf(c1z) + fabsf(c2z);
    // budget: w-eval error (epsf) + affine-z fold error (<=3 f32 roundings)
    float epsz = (2.0f * epsf + 4e-6f) * zs;
    // z-plane coefficients in f64: z(x,y) = zx*px + zy*py + zc0
    double zxd = wx0 * (double)c0z + wx1 * (double)c1z + wx2 * (double)c2z;
    double zyd = wy0 * (double)c0z + wy1 * (double)c1z + wy2 * (double)c2z;
    double zcd = wc0 * (double)c0z + wc1 * (double)c1z + wc2 * (double)c2z;
    FaceRasF fr;
    fr.wx0 = (float)wx0; fr.wy0 = (float)wy0; fr.wc0 = (float)wc0;
    fr.wx1 = (float)wx1; fr.wy1 = (float)wy1; fr.wc1 = (float)wc1;
    fr.wx2 = (float)wx2; fr.wy2 = (float)wy2; fr.wc2 = (float)wc2;
    fr.zx = (float)zxd; fr.zy = (float)zyd; fr.zc0 = (float)zcd;
    fr.epsf = epsf; fr.epsz = epsz; fr.pad0 = 0.f; fr.pad1 = 0.f;
    frasF[i] = fr;
    // EXACT y-range of {dmin >= -band} via the barycentric slab:
    // w0+w1+w2 == 1, so dmin>=-b <=> all w_i>=-b, and y = sum w_i*v_iy over that
    // slab has exact extremes vext + b*(3*vext - sum).
    float band = fmaxf(0.202f, 1.6f * epsf);
    if (fabsf(Araw) < 1e-8f) {
      r0 = 0; r1 = 63;            // degenerate clamp: sum(w) != 1, no bound
    } else {
      float vmin = fminf(v0y, fminf(v1y, v2y));
      float vmax = fmaxf(v0y, fmaxf(v1y, v2y));
      float s3 = v0y + v1y + v2y;
      float b1 = band * 1.05f + 1e-4f;        // slack for f32 rounding
      float ylo = vmin + b1 * (3.f * vmin - s3);
      float yhi = vmax + b1 * (3.f * vmax - s3);
      if (yhi < -1.001f || ylo > 1.001f) { r0 = 1; r1 = 0; }
      else {
        r0 = max(0, (int)floorf((ylo + 1.0f) * 31.5f) - 1);
        r1 = min(63, (int)ceilf((yhi + 1.0f) * 31.5f) + 1);
        if (r0 > r1) { r0 = 1; r1 = 0; }
      }
    }
    // face normal -> vertex normal scatter (f32 atomics, fire-and-forget)
    float e1x = c1x - c0x, e1y = c1y - c0y, e1z = c1z - c0z;
    float e2x = c2x - c0x, e2y = c2y - c0y, e2z = c2z - c0z;
    float nx = e1y * e2z - e1z * e2y;
    float ny = e1z * e2x - e1x * e2z;
    float nz = e1x * e2y - e1y * e2x;
    float* vn0 = vnorm + (size_t)(b * V + i0) * 3;
    float* vn1 = vnorm + (size_t)(b * V + i1) * 3;
    float* vn2 = vnorm + (size_t)(b * V + i2) * 3;
    atomicAdd(vn0 + 0, nx); atomicAdd(vn0 + 1, ny); atomicAdd(vn0 + 2, nz);
    atomicAdd(vn1 + 0, nx); atomicAdd(vn1 + 1, ny); atomicAdd(vn1 + 2, nz);
    atomicAdd(vn2 + 0, nx); atomicAdd(vn2 + 1, ny); atomicAdd(vn2 + 2, nz);
  }
  // wave-aggregated bucket append, trimmed to the wave's row union
  int lane = threadIdx.x & 63;
  bool has = valid && r0 <= r1;
  int rmin = has ? r0 : 64, rmax = has ? r1 : -1;
  for (int off = 32; off; off >>= 1) {
    rmin = min(rmin, __shfl_xor(rmin, off));
    rmax = max(rmax, __shfl_xor(rmax, off));
  }
  for (int r = rmin; r <= rmax; ++r) {
    bool in = has && r >= r0 && r <= r1;
    unsigned long long m = __ballot(in);
    if (m == 0ull) continue;
    int row = (b << 6) | r;
    int leader = __ffsll(m) - 1;
    unsigned base = 0;
    if (lane == leader) base = atomicAdd(&rowcnt[row * CSTR], (unsigned)__popcll(m));
    base = (unsigned)__shfl((int)base, leader);
    if (in) {
      unsigned pos = base + (unsigned)__popcll(m & ((1ull << lane) - 1ull));
      rowbuk[(size_t)row * CAP + pos] = (unsigned)f;   // pos < F == CAP always
    }
  }
}

// f32 screened raster: LDS-staged batches + 4 independent accumulator sets;
// stride-16 row assignment + 1-D chunk-fast grid (R12: fixed the CU-queueing
// hotspot that was the R2-R11 ~100us invariant).
__global__ __launch_bounds__(256) void k_raster(
    const FaceRasF* __restrict__ frasF,
    const unsigned* __restrict__ rowcnt,
    const unsigned* __restrict__ rowbuk,
    float4* __restrict__ pc,
    unsigned CAP, int F, int NC, int P) {
  __shared__ float4 lds[4][2][64 * 3];   // [wave][buf][entry*3] = 24 KB
  int bid = blockIdx.x;
  int chunk = bid % NC;                  // chunk-fast: consecutive IDs spread
  int g = bid / NC;
  int b = g / PPB;
  int q = g % PPB;
  int wv = threadIdx.x >> 6;
  int lane = threadIdx.x & 63;
  int y = q + 16 * wv;                   // stride-16 rows: block-level balance
  int x = lane;
  const double step = 2.0 / 63.0;
  double pxd = (x == HW - 1) ? 1.0 : (x * step - 1.0);
  double pyd = (y == HW - 1) ? 1.0 : (y * step - 1.0);
  float pxf = (float)pxd, pyf = (float)pyd;

  // 4 independent accumulator sets (named: rule #20)
  float zmA = INFINITY, zmB = INFINITY, zmC = INFINITY, zmD = INFINITY;
  float weA = 0.f, weB = 0.f, weC = 0.f, weD = 0.f;
  float lsA = 0.f, lsB = 0.f, lsC = 0.f, lsD = 0.f;
  int bsA = 0, bsB = 0, bsC = 0, bsD = 0;
  bool flA = false, flB = false, flC = false, flD = false;

  auto BODYG = [&](float4 r0, float4 r1, float4 r2,
                   float& zm, float& we, float& ls, int& bs, bool& fl) {
    float w0 = fmaf(r0.x, pxf, r0.w);   // == fmaf(wx,px,fmaf(wy,py,wc))
    float w1 = fmaf(r0.y, pxf, r1.x);
    float w2 = fmaf(r0.z, pxf, r1.y);
    float dmin = fminf(fminf(w0, w1), w2);
    float t = fminf(fmaxf(dmin * 100.0f, -30.0f), 0.0f);
    float pr = __expf(t);               // inside -> t=0 -> pr=1 exactly
    float lg = __logf(fmaf(-pr, 0.99999990f, 1.0f));
    ls += (dmin > -0.2f) ? lg : 0.0f;   // dmin<=-0.2 contributes <=2e-9
    float z = fmaf(r1.z, pxf, r1.w);    // z affine: zx*px + zc
    float ef = r2.x, ez = r2.y;
    bool act = dmin > -ef;
    bool ge0 = dmin >= 0.0f;
    bool contend = (z < zm + ez + we) & (z > -ez);
    fl |= act & (fabsf(dmin) < ef) & contend;          // inside-sign ambiguous
    fl |= act & ge0 & (fabsf(z) < ez);                 // z>0 boundary ambiguous
    fl |= act & ge0 & (z > 0.0f) & (fabsf(z - zm) < ez + we); // z-order ambig.
    bool take = act & ge0 & (z > 0.0f) & (z < zm);     // ties repaired in f64
    zm = take ? z : zm;
    bs = take ? __float_as_int(r2.z) : bs;
    we = take ? ez : we;
  };

  int row = (b << 6) | y;                      // wave-uniform: wave = one row
  unsigned fill = rowcnt[row * CSTR];
  const unsigned* __restrict__ rl = rowbuk + (size_t)row * CAP;
  const float4* __restrict__ fb4 = (const float4*)(frasF + (size_t)b * F);
  unsigned per = (fill + (unsigned)NC - 1) / (unsigned)NC;
  unsigned i0 = min(fill, (unsigned)chunk * per);
  unsigned i1 = min(fill, i0 + per);
  if (i0 < i1) {
    // lane-parallel gather (per-lane vector loads, vmcnt-counted): 64 records
    // in ONE memory latency; issued EARLY, LDS-written LATE. OOR lanes -> null.
    float4 g0, g1, g2;
    auto GATHER = [&](unsigned base) {
      unsigned j = base + (unsigned)lane;
      bool ok = (j < i1);
      unsigned jj = ok ? j : (i1 - 1);
      int fidx = (int)rl[jj];
      size_t o = (size_t)fidx * 4;
      float4 q0 = fb4[o + 0], q1 = fb4[o + 1], q2 = fb4[o + 2], q3 = fb4[o + 3];
      float ce0 = fmaf(q0.y, pyf, q0.z);     // wy*py+wc (py wave-uniform)
      float ce1 = fmaf(q1.x, pyf, q1.y);
      float ce2 = fmaf(q1.w, pyf, q2.x);
      float zc  = fmaf(q2.z, pyf, q2.w);     // zy*py+zc0
      // null record for OOR: ce0=-1e30 -> dmin=-1e30 -> all gates false
      g0 = make_float4(ok ? q0.x : 0.f, ok ? q0.w : 0.f, ok ? q1.z : 0.f,
                       ok ? ce0 : -1e30f);
      g1 = make_float4(ok ? ce1 : 0.f, ok ? ce2 : 0.f, ok ? q2.y : 0.f,
                       ok ? zc : 0.f);
      g2 = make_float4(ok ? q3.x : 0.f, ok ? q3.y : 0.f,
                       __int_as_float(ok ? fidx : 0), 0.f);
    };
    auto WRITE = [&](int buf) {
      lds[wv][buf][lane * 3 + 0] = g0;
      lds[wv][buf][lane * 3 + 1] = g1;
      lds[wv][buf][lane * 3 + 2] = g2;
    };
    GATHER(i0);
    WRITE(0);
    unsigned nb = (i1 - i0 + 63) >> 6;
    for (unsigned bi = 0; bi < nb; ++bi) {
      if (bi + 1 < nb) GATHER(i0 + (bi + 1) * 64);   // next batch in flight
      int n = (int)min(64u, i1 - i0 - bi * 64);
      int n4 = (n + 3) & ~3;                         // pad to group of 4 (nulls)
      const float4* __restrict__ L = lds[wv][bi & 1];
      for (int k = 0; k < n4; k += 4) {
        // 12 named loads first (ds_reads batch-issued), then 4 indep chains
        float4 a0 = L[(k+0)*3+0], a1 = L[(k+0)*3+1], a2 = L[(k+0)*3+2];
        float4 b0 = L[(k+1)*3+0], b1 = L[(k+1)*3+1], b2 = L[(k+1)*3+2];
        float4 c0 = L[(k+2)*3+0], c1 = L[(k+2)*3+1], c2 = L[(k+2)*3+2];
        float4 d0 = L[(k+3)*3+0], d1 = L[(k+3)*3+1], d2 = L[(k+3)*3+2];
        BODYG(a0, a1, a2, zmA, weA, lsA, bsA, flA);
        BODYG(b0, b1, b2, zmB, weB, lsB, bsB, flB);
        BODYG(c0, c1, c2, zmC, weC, lsC, bsC, flC);
        BODYG(d0, d1, d2, zmD, weD, lsD, bsD, flD);
      }
      if (bi + 1 < nb) WRITE((bi + 1) & 1);          // write after walk
    }
  }
  // merge the 4 partials with the k_final cross-chunk rules (NaN-safe)
  float zmin = INFINITY, weps = 0.f, lsum = 0.f;
  int best = 0;
  bool flag = false;
  auto MERGE = [&](float z, float e, float l, int bsx, bool flx) {
    flag |= flx;
    flag |= fabsf(z - zmin) < (e + weps + 2e-6f);
    if (z < zmin) { zmin = z; best = bsx; weps = e; }
    lsum += l;
  };
  MERGE(zmA, weA, lsA, bsA, flA);
  MERGE(zmB, weB, lsB, bsB, flB);
  MERGE(zmC, weC, lsC, bsC, flC);
  MERGE(zmD, weD, lsD, bsD, flD);
  int p = b * (HW * HW) + (y << 6) + x;
  unsigned pbv = (unsigned)best | (flag ? 0x80000000u : 0u);
  pc[(size_t)chunk * P + p] = make_float4(zmin, lsum, weps, __uint_as_float(pbv));
}

// exact f64 winner recompute + gather-interpolate + output write (not improb)
__device__ void write_winner(const float* __restrict__ vs_cam,
                             const int* __restrict__ faces,
                             const float* __restrict__ vnorm,
                             const float* __restrict__ attribs,
                             float* __restrict__ out, int P,
                             int b, int V, int F, int pix,
                             int best, bool covered) {
  int p = b * (HW * HW) + pix;
  float imn[3] = {0.f, 0.f, 0.f};
  float ima[3] = {0.f, 0.f, 0.f};
  if (covered) {
    int x = pix & 63, y = pix >> 6;
    const double step = 2.0 / 63.0;
    double px = (x == HW - 1) ? 1.0 : (x * step - 1.0);
    double py = (y == HW - 1) ? 1.0 : (y * step - 1.0);
    int vid[3] = {faces[best * 3 + 0], faces[best * 3 + 1], faces[best * 3 + 2]};
    const float* c0 = vs_cam + (size_t)(b * V + vid[0]) * 3;
    const float* c1 = vs_cam + (size_t)(b * V + vid[1]) * 3;
    const float* c2 = vs_cam + (size_t)(b * V + vid[2]) * 3;
    float v0x = c0[0] / c0[2], v0y = c0[1] / c0[2];
    float v1x = c1[0] / c1[2], v1y = c1[1] / c1[2];
    float v2x = c2[0] / c2[2], v2y = c2[1] / c2[2];
    float dx0 = v2x - v1x, dy0 = v2y - v1y;
    float dx1 = v0x - v2x, dy1 = v0y - v2y;
    float dx2 = v1x - v0x, dy2 = v1y - v0y;
    float A = dx2 * (v2y - v0y) - dy2 * (v2x - v0x);
    if (fabsf(A) < 1e-8f) A = 1e-8f;
    double invA = 1.0 / (double)A;
    double a0 = (double)dx0 * (py - (double)v1y) - (double)dy0 * (px - (double)v1x);
    double a1 = (double)dx1 * (py - (double)v2y) - (double)dy1 * (px - (double)v2x);
    double a2 = (double)dx2 * (py - (double)v0y) - (double)dy2 * (px - (double)v0x);
    double wk[3] = {a0 * invA, a1 * invA, a2 * invA};
    double v[6] = {0, 0, 0, 0, 0, 0};
#pragma unroll
    for (int k = 0; k < 3; ++k) {
      const float* n = vnorm + (size_t)(b * V + vid[k]) * 3;
      float nx = n[0], ny = n[1], nz = n[2];
      float nrm = sqrtf(nx * nx + ny * ny + nz * nz) + 1e-10f;  // f32, like ref
      const float* at = attribs + (((size_t)(b * F + best)) * 3 + k) * 3;
      v[0] += wk[k] * (double)(nx / nrm);
      v[1] += wk[k] * (double)(ny / nrm);
      v[2] += wk[k] * (double)(nz / nrm);
      v[3] += wk[k] * (double)at[0];
      v[4] += wk[k] * (double)at[1];
      v[5] += wk[k] * (double)at[2];
    }
    double nn = sqrt(v[0] * v[0] + v[1] * v[1] + v[2] * v[2]) + 1e-10;
    imn[0] = (float)(v[0] / nn);
    imn[1] = (float)(v[1] / nn);
    imn[2] = (float)(v[2] / nn);
    ima[0] = (float)v[3]; ima[1] = (float)v[4]; ima[2] = (float)v[5];
  }
  float* o_n = out;
  float* o_a = out + (size_t)P * 3;
  float* o_p = out + (size_t)P * 6;
  float* o_i = o_p + P;
  o_n[(size_t)p * 3 + 0] = imn[0];
  o_n[(size_t)p * 3 + 1] = imn[1];
  o_n[(size_t)p * 3 + 2] = imn[2];
  o_a[(size_t)p * 3 + 0] = ima[0];
  o_a[(size_t)p * 3 + 1] = ima[1];
  o_a[(size_t)p * 3 + 2] = ima[2];
  o_i[p] = covered ? (float)best : -1.0f;
}

__global__ void k_final(const float* __restrict__ vs_cam,
                        const int* __restrict__ faces,
                        const float* __restrict__ vnorm,
                        const float* __restrict__ attribs,
                        const float4* __restrict__ pc,
                        float* __restrict__ out,
                        int* __restrict__ cnt, int* __restrict__ list,
                        int B, int V, int F, int NC) {
  int p = blockIdx.x * blockDim.x + threadIdx.x;
  int P = B * HW * HW;
  if (p >= P) return;
  float zmin = INFINITY, weps = 0.f, lsum = 0.f;
  int best = 0;
  bool flag = false;
  for (int c = 0; c < NC; ++c) {
    float4 q = pc[(size_t)c * P + p];
    float z = q.x;
    float e = q.z;
    unsigned pb = __float_as_uint(q.w);
    flag |= (pb >> 31) != 0;
    flag |= fabsf(z - zmin) < (e + weps + 2e-6f);  // cross-chunk near-tie (NaN-safe)
    if (z < zmin) { zmin = z; best = (int)(pb & 0x7fffffffu); weps = e; }
    lsum += q.y;
  }
  bool covered = (zmin < 1e38f);
  int b = p >> 12;            // HW*HW = 4096
  int pix = p & 4095;
  write_winner(vs_cam, faces, vnorm, attribs, out, P, b, V, F, pix, best, covered);
  float* o_p = out + (size_t)P * 6;
  o_p[p] = 1.0f - __expf(lsum);
  if (flag) {
    int s = atomicAdd(cnt, 1);
    list[s] = p;
  }
}

// exact f64 re-argmin for flagged pixels: ONE BLOCK (4 waves, 256 lanes) per
// pixel. R15 lesson: every screen variant (continue / ballot-compact) re-created
// the per-iteration stall (cross-lane ops consume loads in-iteration). Keep the
// R12-PROVEN branchless full-f64 body verbatim and cut the serial chain 4x by
// striding f across 256 lanes (24 iters instead of 94); block-level
// (z,f)-lexicographic reduce preserves first-occurrence argmin.
__global__ __launch_bounds__(256) void k_repair(
    const float* __restrict__ vs_cam,
    const int* __restrict__ faces,
    const float* __restrict__ vnorm,
    const float* __restrict__ attribs,
    const int* __restrict__ cnt, const int* __restrict__ list,
    float* __restrict__ out, int B, int V, int F) {
  __shared__ double zred[4];
  __shared__ int bred[4];
  int P = B * HW * HW;
  int tid = threadIdx.x;
  int wv = tid >> 6;
  int lane = tid & 63;
  int n = cnt[0];
  for (int i = blockIdx.x; i < n; i += gridDim.x) {
    int p = list[i];
    int b = p >> 12;
    int pix = p & 4095;
    int x = pix & 63, y = pix >> 6;
    const double step = 2.0 / 63.0;
    double px = (x == HW - 1) ? 1.0 : (x * step - 1.0);
    double py = (y == HW - 1) ? 1.0 : (y * step - 1.0);
    double zmin = INFINITY;
    int best = 0x7fffffff;
    for (int f = tid; f < F; f += 256) {     // 256-lane stride: chain / 4
      int i0 = faces[f * 3 + 0], i1 = faces[f * 3 + 1], i2 = faces[f * 3 + 2];
      const float* c0 = vs_cam + (size_t)(b * V + i0) * 3;
      const float* c1 = vs_cam + (size_t)(b * V + i1) * 3;
      const float* c2 = vs_cam + (size_t)(b * V + i2) * 3;
      float c0z = c0[2], c1z = c1[2], c2z = c2[2];
      float v0x = c0[0] / c0z, v0y = c0[1] / c0z;
      float v1x = c1[0] / c1z, v1y = c1[1] / c1z;
      float v2x = c2[0] / c2z, v2y = c2[1] / c2z;
      float dx0 = v2x - v1x, dy0 = v2y - v1y;
      float dx1 = v0x - v2x, dy1 = v0y - v2y;
      float dx2 = v1x - v0x, dy2 = v1y - v0y;
      float A = dx2 * (v2y - v0y) - dy2 * (v2x - v0x);
      if (fabsf(A) < 1e-8f) A = 1e-8f;
      double invA = 1.0 / (double)A;
      double a0 = (double)dx0 * (py - (double)v1y) - (double)dy0 * (px - (double)v1x);
      double a1 = (double)dx1 * (py - (double)v2y) - (double)dy1 * (px - (double)v2x);
      double a2 = (double)dx2 * (py - (double)v0y) - (double)dy2 * (px - (double)v0x);
      double w0 = a0 * invA, w1 = a1 * invA, w2 = a2 * invA;
      bool inside = (w0 >= 0.0) & (w1 >= 0.0) & (w2 >= 0.0);
      double z = (w0 * (double)c0z + w1 * (double)c1z) + w2 * (double)c2z;
      // per-lane visits ascend in f; strict < keeps first occurrence
      if (inside & (z > 0.0) & (z < zmin)) { zmin = z; best = f; }
    }
    // lexicographic (z, idx) wave reduce
    for (int off = 32; off; off >>= 1) {
      double zo = __shfl_down(zmin, off);
      int bo = __shfl_down(best, off);
      if ((zo < zmin) || ((zo == zmin) && (bo < best))) { zmin = zo; best = bo; }
    }
    if (lane == 0) { zred[wv] = zmin; bred[wv] = best; }
    __syncthreads();
    if (tid == 0) {
      double zm = zred[0];
      int bs = bred[0];
#pragma unroll
      for (int k = 1; k < 4; ++k) {
        double zo = zred[k];
        int bo = bred[k];
        if ((zo < zm) || ((zo == zm) && (bo < bs))) { zm = zo; bs = bo; }
      }
      bool covered = (zm < 1e300);
      write_winner(vs_cam, faces, vnorm, attribs, out, P, b, V, F, pix, bs, covered);
    }
    __syncthreads();   // zred/bred reuse safety across grid-stride iterations
  }
}

extern "C" void kernel_launch(void* const* d_in, const int* in_sizes, int n_in,
                              void* d_out, int out_size, void* d_ws, size_t ws_size,
                              hipStream_t stream) {
  const float* vert    = (const float*)d_in[0];
  const int*   faces   = (const int*)d_in[1];
  const float* attribs = (const float*)d_in[2];
  const float* rot     = (const float*)d_in[3];
  const float* trans   = (const float*)d_in[4];
  int B = in_sizes[4] / 3;
  int V = in_sizes[0] / (3 * B);
  int F = in_sizes[1] / 3;
  int P = B * HW * HW;
  int NR = B * HW;                              // total (b,row) buckets

  size_t CAP = (size_t)F;                       // exact worst case, no overflow
  size_t szFras  = sizeof(FaceRasF) * (size_t)B * F;
  size_t szBuk   = 4ull * (size_t)NR * CAP;
  size_t szVs    = 12ull * (size_t)B * V;
  size_t szVn    = 12ull * (size_t)B * V;
  size_t szRowC  = 4ull * (size_t)NR * CSTR;    // rowcnt (strided)
  size_t szCnt   = 4;
  size_t szPlist = 4ull * (size_t)P;
  size_t fixed   = szFras + szBuk + szVs + szVn + szRowC + szCnt + szPlist + 1024;

  int NC = 32;                                  // chunks
  while (NC > 2 && fixed + (size_t)P * 16ull * NC > ws_size) NC >>= 1;

  char* w = (char*)d_ws;
  FaceRasF* frasF  = (FaceRasF*)w; w += szFras;            // 64B-aligned
  float4* pc       = (float4*)w;   w += (size_t)P * 16ull * NC;
  unsigned* rowbuk = (unsigned*)w; w += szBuk;
  float* vs_cam    = (float*)w;    w += szVs;
  float* vnorm     = (float*)w;    w += szVn;
  unsigned* rowcnt = (unsigned*)w; w += szRowC;            // contiguous zero region:
  int* cnt         = (int*)w;      w += szCnt;             //   rowcnt + cnt
  int* list        = (int*)w;      /* P entries */
  int nzero = NR * CSTR + 1;

  k_prep<<<(B * V + 255) / 256, 256, 0, stream>>>(vert, rot, trans, vs_cam,
                                                  vnorm, rowcnt, nzero, B, V);
  dim3 fg((unsigned)((F + 255) / 256), (unsigned)B);
  k_facepre<<<fg, 256, 0, stream>>>(vs_cam, faces, frasF, vnorm, rowcnt,
                                    rowbuk, (unsigned)CAP, B, V, F);
  // 1-D chunk-fast grid: consecutive block IDs = chunks of the same pixgrp,
  // spread across CUs/XCDs; stride-16 rows inside blocks balance the rest.
  k_raster<<<(unsigned)(B * PPB * NC), 256, 0, stream>>>(frasF, rowcnt, rowbuk,
                                                         pc, (unsigned)CAP, F,
                                                         NC, P);
  k_final<<<(P + 255) / 256, 256, 0, stream>>>(vs_cam, faces, vnorm, attribs,
                                               pc, (float*)d_out, cnt, list,
                                               B, V, F, NC);
  k_repair<<<2048, 256, 0, stream>>>(vs_cam, faces, vnorm, attribs,
                                     cnt, list, (float*)d_out, B, V, F);
}

// Round 17
// 195.865 us; speedup vs baseline: 1.6350x; 1.0206x over previous
//
#include <hip/hip_runtime.h>
#include <math.h>

#define HW 64
#define PPB 16   // pixblocks per image: block q's 4 waves take rows q+16*wv
#define CSTR 8   // row-counter stride (words) to spread atomics across L2 channels

// f32 fast-raster record: 16 floats = 64 B
// float4 view: q0=(wx0,wy0,wc0,wx1) q1=(wy1,wc1,wx2,wy2) q2=(wc2,zx,zy,zc0) q3=(epsf,epsz,pad,pad)
// z is affine in screen coords: z(x,y) = zx*px + zy*py + zc0 (folded in f64).
struct FaceRasF {
  float wx0, wy0, wc0;
  float wx1, wy1, wc1;
  float wx2, wy2, wc2;
  float zx, zy, zc0;
  float epsf, epsz;
  float pad0, pad1;
};

// transform + ALL zero-init (vnorm, rowcnt, cnt): memset dispatch folded in.
__global__ void k_prep(const float* __restrict__ vert,
                       const float* __restrict__ rot,
                       const float* __restrict__ trans,
                       float* __restrict__ vs_cam,
                       float* __restrict__ vnorm,
                       unsigned* __restrict__ zerobase, int nzero,
                       int B, int V) {
  int i = blockIdx.x * blockDim.x + threadIdx.x;
  if (i < nzero) zerobase[i] = 0u;
  if (i >= B * V) return;
  int b = i / V;
  float x = vert[i * 3 + 0], y = vert[i * 3 + 1], z = vert[i * 3 + 2];
  const float* R = rot + b * 9;
  const float* t = trans + b * 3;
  vs_cam[i * 3 + 0] = ((x * R[0] + y * R[1]) + z * R[2]) + t[0];
  vs_cam[i * 3 + 1] = ((x * R[3] + y * R[4]) + z * R[5]) + t[1];
  vs_cam[i * 3 + 2] = ((x * R[6] + y * R[7]) + z * R[8]) + t[2];
  vnorm[i * 3 + 0] = 0.f;
  vnorm[i * 3 + 1] = 0.f;
  vnorm[i * 3 + 2] = 0.f;
}

// face precompute + DIRECT index-bucket emit (CAP=F exact worst case).
// grid: ((F+255)/256, B) so each wave has uniform b (ballot aggregation).
__global__ void k_facepre(const float* __restrict__ vs_cam,
                          const int* __restrict__ faces,
                          FaceRasF* __restrict__ frasF,
                          float* __restrict__ vnorm,
                          unsigned* __restrict__ rowcnt,
                          unsigned* __restrict__ rowbuk,
                          unsigned CAP, int B, int V, int F) {
  int f = blockIdx.x * blockDim.x + threadIdx.x;
  int b = blockIdx.y;
  bool valid = (f < F);
  int r0 = 1, r1 = 0;
  if (valid) {
    int i = b * F + f;
    int i0 = faces[f * 3 + 0], i1 = faces[f * 3 + 1], i2 = faces[f * 3 + 2];
    const float* c0 = vs_cam + (size_t)(b * V + i0) * 3;
    const float* c1 = vs_cam + (size_t)(b * V + i1) * 3;
    const float* c2 = vs_cam + (size_t)(b * V + i2) * 3;
    float c0x = c0[0], c0y = c0[1], c0z = c0[2];
    float c1x = c1[0], c1y = c1[1], c1z = c1[2];
    float c2x = c2[0], c2y = c2[1], c2z = c2[2];
    float v0x = c0x / c0z, v0y = c0y / c0z;
    float v1x = c1x / c1z, v1y = c1y / c1z;
    float v2x = c2x / c2z, v2y = c2y / c2z;
    float dx0 = v2x - v1x, dy0 = v2y - v1y;   // edge(v1,v2), anchor v1
    float dx1 = v0x - v2x, dy1 = v0y - v2y;   // edge(v2,v0), anchor v2
    float dx2 = v1x - v0x, dy2 = v1y - v0y;   // edge(v0,v1), anchor v0
    float Araw = dx2 * (v2y - v0y) - dy2 * (v2x - v0x);
    float A = (fabsf(Araw) < 1e-8f) ? 1e-8f : Araw;
    double invA = 1.0 / (double)A;
    double wx0 = -(double)dy0 * invA, wy0 = (double)dx0 * invA;
    double wc0 = ((double)dy0 * (double)v1x - (double)dx0 * (double)v1y) * invA;
    double wx1 = -(double)dy1 * invA, wy1 = (double)dx1 * invA;
    double wc1 = ((double)dy1 * (double)v2x - (double)dx1 * (double)v2y) * invA;
    double wx2 = -(double)dy2 * invA, wy2 = (double)dx2 * invA;
    double wc2 = ((double)dy2 * (double)v0x - (double)dx2 * (double)v0y) * invA;
    double m0 = fabs(wx0) + fabs(wy0) + fabs(wc0);
    double m1 = fabs(wx1) + fabs(wy1) + fabs(wc1);
    double m2 = fabs(wx2) + fabs(wy2) + fabs(wc2);
    double mm = fmax(fmax(m0, m1), m2);
    float epsf = fmaxf((float)(6e-7 * mm), 3e-7f);
    float zs = fabsf(c0z) + fabsf(c1z) + fabsf(c2z);
    // budget: w-eval error (epsf) + affine-z fold error (<=3 f32 roundings)
    float epsz = (2.0f * epsf + 4e-6f) * zs;
    // z-plane coefficients in f64: z(x,y) = zx*px + zy*py + zc0
    double zxd = wx0 * (double)c0z + wx1 * (double)c1z + wx2 * (double)c2z;
    double zyd = wy0 * (double)c0z + wy1 * (double)c1z + wy2 * (double)c2z;
    double zcd = wc0 * (double)c0z + wc1 * (double)c1z + wc2 * (double)c2z;
    FaceRasF fr;
    fr.wx0 = (float)wx0; fr.wy0 = (float)wy0; fr.wc0 = (float)wc0;
    fr.wx1 = (float)wx1; fr.wy1 = (float)wy1; fr.wc1 = (float)wc1;
    fr.wx2 = (float)wx2; fr.wy2 = (float)wy2; fr.wc2 = (float)wc2;
    fr.zx = (float)zxd; fr.zy = (float)zyd; fr.zc0 = (float)zcd;
    fr.epsf = epsf; fr.epsz = epsz; fr.pad0 = 0.f; fr.pad1 = 0.f;
    frasF[i] = fr;
    // EXACT y-range of {dmin >= -band} via the barycentric slab:
    // w0+w1+w2 == 1, so dmin>=-b <=> all w_i>=-b, and y = sum w_i*v_iy over that
    // slab has exact extremes vext + b*(3*vext - sum).
    float band = fmaxf(0.202f, 1.6f * epsf);
    if (fabsf(Araw) < 1e-8f) {
      r0 = 0; r1 = 63;            // degenerate clamp: sum(w) != 1, no bound
    } else {
      float vmin = fminf(v0y, fminf(v1y, v2y));
      float vmax = fmaxf(v0y, fmaxf(v1y, v2y));
      float s3 = v0y + v1y + v2y;
      float b1 = band * 1.05f + 1e-4f;        // slack for f32 rounding
      float ylo = vmin + b1 * (3.f * vmin - s3);
      float yhi = vmax + b1 * (3.f * vmax - s3);
      if (yhi < -1.001f || ylo > 1.001f) { r0 = 1; r1 = 0; }
      else {
        r0 = max(0, (int)floorf((ylo + 1.0f) * 31.5f) - 1);
        r1 = min(63, (int)ceilf((yhi + 1.0f) * 31.5f) + 1);
        if (r0 > r1) { r0 = 1; r1 = 0; }
      }
    }
    // face normal -> vertex normal scatter (f32 atomics, fire-and-forget)
    float e1x = c1x - c0x, e1y = c1y - c0y, e1z = c1z - c0z;
    float e2x = c2x - c0x, e2y = c2y - c0y, e2z = c2z - c0z;
    float nx = e1y * e2z - e1z * e2y;
    float ny = e1z * e2x - e1x * e2z;
    float nz = e1x * e2y - e1y * e2x;
    float* vn0 = vnorm + (size_t)(b * V + i0) * 3;
    float* vn1 = vnorm + (size_t)(b * V + i1) * 3;
    float* vn2 = vnorm + (size_t)(b * V + i2) * 3;
    atomicAdd(vn0 + 0, nx); atomicAdd(vn0 + 1, ny); atomicAdd(vn0 + 2, nz);
    atomicAdd(vn1 + 0, nx); atomicAdd(vn1 + 1, ny); atomicAdd(vn1 + 2, nz);
    atomicAdd(vn2 + 0, nx); atomicAdd(vn2 + 1, ny); atomicAdd(vn2 + 2, nz);
  }
  // wave-aggregated bucket append, trimmed to the wave's row union
  int lane = threadIdx.x & 63;
  bool has = valid && r0 <= r1;
  int rmin = has ? r0 : 64, rmax = has ? r1 : -1;
  for (int off = 32; off; off >>= 1) {
    rmin = min(rmin, __shfl_xor(rmin, off));
    rmax = max(rmax, __shfl_xor(rmax, off));
  }
  for (int r = rmin; r <= rmax; ++r) {
    bool in = has && r >= r0 && r <= r1;
    unsigned long long m = __ballot(in);
    if (m == 0ull) continue;
    int row = (b << 6) | r;
    int leader = __ffsll(m) - 1;
    unsigned base = 0;
    if (lane == leader) base = atomicAdd(&rowcnt[row * CSTR], (unsigned)__popcll(m));
    base = (unsigned)__shfl((int)base, leader);
    if (in) {
      unsigned pos = base + (unsigned)__popcll(m & ((1ull << lane) - 1ull));
      rowbuk[(size_t)row * CAP + pos] = (unsigned)f;   // pos < F == CAP always
    }
  }
}

// f32 screened raster: LDS-staged batches + 4 independent accumulator sets;
// stride-16 row assignment + 1-D chunk-fast grid (R12 balance fix).
// R16: SINGLE LDS buffer (12 KB, was 24): GATHER (global->regs) is issued
// before the walk and WRITE (regs->LDS) lands after the walk frees the buffer
// — same overlap as the double buffer, half the LDS -> ~13 blocks/CU
// co-resident (was 6) = 2x the waves hiding the per-entry stall.
__global__ __launch_bounds__(256) void k_raster(
    const FaceRasF* __restrict__ frasF,
    const unsigned* __restrict__ rowcnt,
    const unsigned* __restrict__ rowbuk,
    float4* __restrict__ pc,
    unsigned CAP, int F, int NC, int P) {
  __shared__ float4 lds[4][64 * 3];      // [wave][entry*3] = 12 KB
  int bid = blockIdx.x;
  int chunk = bid % NC;                  // chunk-fast: consecutive IDs spread
  int g = bid / NC;
  int b = g / PPB;
  int q = g % PPB;
  int wv = threadIdx.x >> 6;
  int lane = threadIdx.x & 63;
  int y = q + 16 * wv;                   // stride-16 rows: block-level balance
  int x = lane;
  const double step = 2.0 / 63.0;
  double pxd = (x == HW - 1) ? 1.0 : (x * step - 1.0);
  double pyd = (y == HW - 1) ? 1.0 : (y * step - 1.0);
  float pxf = (float)pxd, pyf = (float)pyd;

  // 4 independent accumulator sets (named: rule #20)
  float zmA = INFINITY, zmB = INFINITY, zmC = INFINITY, zmD = INFINITY;
  float weA = 0.f, weB = 0.f, weC = 0.f, weD = 0.f;
  float lsA = 0.f, lsB = 0.f, lsC = 0.f, lsD = 0.f;
  int bsA = 0, bsB = 0, bsC = 0, bsD = 0;
  bool flA = false, flB = false, flC = false, flD = false;

  auto BODYG = [&](float4 r0, float4 r1, float4 r2,
                   float& zm, float& we, float& ls, int& bs, bool& fl) {
    float w0 = fmaf(r0.x, pxf, r0.w);   // == fmaf(wx,px,fmaf(wy,py,wc))
    float w1 = fmaf(r0.y, pxf, r1.x);
    float w2 = fmaf(r0.z, pxf, r1.y);
    float dmin = fminf(fminf(w0, w1), w2);
    float t = fminf(fmaxf(dmin * 100.0f, -30.0f), 0.0f);
    float pr = __expf(t);               // inside -> t=0 -> pr=1 exactly
    float lg = __logf(fmaf(-pr, 0.99999990f, 1.0f));
    ls += (dmin > -0.2f) ? lg : 0.0f;   // dmin<=-0.2 contributes <=2e-9
    float z = fmaf(r1.z, pxf, r1.w);    // z affine: zx*px + zc
    float ef = r2.x, ez = r2.y;
    bool act = dmin > -ef;
    bool ge0 = dmin >= 0.0f;
    bool contend = (z < zm + ez + we) & (z > -ez);
    fl |= act & (fabsf(dmin) < ef) & contend;          // inside-sign ambiguous
    fl |= act & ge0 & (fabsf(z) < ez);                 // z>0 boundary ambiguous
    fl |= act & ge0 & (z > 0.0f) & (fabsf(z - zm) < ez + we); // z-order ambig.
    bool take = act & ge0 & (z > 0.0f) & (z < zm);     // ties repaired in f64
    zm = take ? z : zm;
    bs = take ? __float_as_int(r2.z) : bs;
    we = take ? ez : we;
  };

  int row = (b << 6) | y;                      // wave-uniform: wave = one row
  unsigned fill = rowcnt[row * CSTR];
  const unsigned* __restrict__ rl = rowbuk + (size_t)row * CAP;
  const float4* __restrict__ fb4 = (const float4*)(frasF + (size_t)b * F);
  unsigned per = (fill + (unsigned)NC - 1) / (unsigned)NC;
  unsigned i0 = min(fill, (unsigned)chunk * per);
  unsigned i1 = min(fill, i0 + per);
  if (i0 < i1) {
    // lane-parallel gather (per-lane vector loads, vmcnt-counted): 64 records
    // in ONE memory latency; issued EARLY, LDS-written LATE. OOR lanes -> null.
    float4 g0, g1, g2;
    auto GATHER = [&](unsigned base) {
      unsigned j = base + (unsigned)lane;
      bool ok = (j < i1);
      unsigned jj = ok ? j : (i1 - 1);
      int fidx = (int)rl[jj];
      size_t o = (size_t)fidx * 4;
      float4 q0 = fb4[o + 0], q1 = fb4[o + 1], q2 = fb4[o + 2], q3 = fb4[o + 3];
      float ce0 = fmaf(q0.y, pyf, q0.z);     // wy*py+wc (py wave-uniform)
      float ce1 = fmaf(q1.x, pyf, q1.y);
      float ce2 = fmaf(q1.w, pyf, q2.x);
      float zc  = fmaf(q2.z, pyf, q2.w);     // zy*py+zc0
      // null record for OOR: ce0=-1e30 -> dmin=-1e30 -> all gates false
      g0 = make_float4(ok ? q0.x : 0.f, ok ? q0.w : 0.f, ok ? q1.z : 0.f,
                       ok ? ce0 : -1e30f);
      g1 = make_float4(ok ? ce1 : 0.f, ok ? ce2 : 0.f, ok ? q2.y : 0.f,
                       ok ? zc : 0.f);
      g2 = make_float4(ok ? q3.x : 0.f, ok ? q3.y : 0.f,
                       __int_as_float(ok ? fidx : 0), 0.f);
    };
    auto WRITE = [&]() {                       // per-wave private: no barrier
      lds[wv][lane * 3 + 0] = g0;
      lds[wv][lane * 3 + 1] = g1;
      lds[wv][lane * 3 + 2] = g2;
    };
    GATHER(i0);
    WRITE();
    unsigned nb = (i1 - i0 + 63) >> 6;
    for (unsigned bi = 0; bi < nb; ++bi) {
      if (bi + 1 < nb) GATHER(i0 + (bi + 1) * 64);   // next batch in flight
      int n = (int)min(64u, i1 - i0 - bi * 64);
      int n4 = (n + 3) & ~3;                         // pad to group of 4 (nulls)
      const float4* __restrict__ L = lds[wv];
      for (int k = 0; k < n4; k += 4) {
        // 12 named loads first (ds_reads batch-issued), then 4 indep chains
        float4 a0 = L[(k+0)*3+0], a1 = L[(k+0)*3+1], a2 = L[(k+0)*3+2];
        float4 b0 = L[(k+1)*3+0], b1 = L[(k+1)*3+1], b2 = L[(k+1)*3+2];
        float4 c0 = L[(k+2)*3+0], c1 = L[(k+2)*3+1], c2 = L[(k+2)*3+2];
        float4 d0 = L[(k+3)*3+0], d1 = L[(k+3)*3+1], d2 = L[(k+3)*3+2];
        BODYG(a0, a1, a2, zmA, weA, lsA, bsA, flA);
        BODYG(b0, b1, b2, zmB, weB, lsB, bsB, flB);
        BODYG(c0, c1, c2, zmC, weC, lsC, bsC, flC);
        BODYG(d0, d1, d2, zmD, weD, lsD, bsD, flD);
      }
      if (bi + 1 < nb) WRITE();                // buffer freed by the walk above
    }
  }
  // merge the 4 partials with the k_final cross-chunk rules (NaN-safe)
  float zmin = INFINITY, weps = 0.f, lsum = 0.f;
  int best = 0;
  bool flag = false;
  auto MERGE = [&](float z, float e, float l, int bsx, bool flx) {
    flag |= flx;
    flag |= fabsf(z - zmin) < (e + weps + 2e-6f);
    if (z < zmin) { zmin = z; best = bsx; weps = e; }
    lsum += l;
  };
  MERGE(zmA, weA, lsA, bsA, flA);
  MERGE(zmB, weB, lsB, bsB, flB);
  MERGE(zmC, weC, lsC, bsC, flC);
  MERGE(zmD, weD, lsD, bsD, flD);
  int p = b * (HW * HW) + (y << 6) + x;
  unsigned pbv = (unsigned)best | (flag ? 0x80000000u : 0u);
  pc[(size_t)chunk * P + p] = make_float4(zmin, lsum, weps, __uint_as_float(pbv));
}

// exact f64 winner recompute + gather-interpolate + output write (not improb)
__device__ void write_winner(const float* __restrict__ vs_cam,
                             const int* __restrict__ faces,
                             const float* __restrict__ vnorm,
                             const float* __restrict__ attribs,
                             float* __restrict__ out, int P,
                             int b, int V, int F, int pix,
                             int best, bool covered) {
  int p = b * (HW * HW) + pix;
  float imn[3] = {0.f, 0.f, 0.f};
  float ima[3] = {0.f, 0.f, 0.f};
  if (covered) {
    int x = pix & 63, y = pix >> 6;
    const double step = 2.0 / 63.0;
    double px = (x == HW - 1) ? 1.0 : (x * step - 1.0);
    double py = (y == HW - 1) ? 1.0 : (y * step - 1.0);
    int vid[3] = {faces[best * 3 + 0], faces[best * 3 + 1], faces[best * 3 + 2]};
    const float* c0 = vs_cam + (size_t)(b * V + vid[0]) * 3;
    const float* c1 = vs_cam + (size_t)(b * V + vid[1]) * 3;
    const float* c2 = vs_cam + (size_t)(b * V + vid[2]) * 3;
    float v0x = c0[0] / c0[2], v0y = c0[1] / c0[2];
    float v1x = c1[0] / c1[2], v1y = c1[1] / c1[2];
    float v2x = c2[0] / c2[2], v2y = c2[1] / c2[2];
    float dx0 = v2x - v1x, dy0 = v2y - v1y;
    float dx1 = v0x - v2x, dy1 = v0y - v2y;
    float dx2 = v1x - v0x, dy2 = v1y - v0y;
    float A = dx2 * (v2y - v0y) - dy2 * (v2x - v0x);
    if (fabsf(A) < 1e-8f) A = 1e-8f;
    double invA = 1.0 / (double)A;
    double a0 = (double)dx0 * (py - (double)v1y) - (double)dy0 * (px - (double)v1x);
    double a1 = (double)dx1 * (py - (double)v2y) - (double)dy1 * (px - (double)v2x);
    double a2 = (double)dx2 * (py - (double)v0y) - (double)dy2 * (px - (double)v0x);
    double wk[3] = {a0 * invA, a1 * invA, a2 * invA};
    double v[6] = {0, 0, 0, 0, 0, 0};
#pragma unroll
    for (int k = 0; k < 3; ++k) {
      const float* n = vnorm + (size_t)(b * V + vid[k]) * 3;
      float nx = n[0], ny = n[1], nz = n[2];
      float nrm = sqrtf(nx * nx + ny * ny + nz * nz) + 1e-10f;  // f32, like ref
      const float* at = attribs + (((size_t)(b * F + best)) * 3 + k) * 3;
      v[0] += wk[k] * (double)(nx / nrm);
      v[1] += wk[k] * (double)(ny / nrm);
      v[2] += wk[k] * (double)(nz / nrm);
      v[3] += wk[k] * (double)at[0];
      v[4] += wk[k] * (double)at[1];
      v[5] += wk[k] * (double)at[2];
    }
    double nn = sqrt(v[0] * v[0] + v[1] * v[1] + v[2] * v[2]) + 1e-10;
    imn[0] = (float)(v[0] / nn);
    imn[1] = (float)(v[1] / nn);
    imn[2] = (float)(v[2] / nn);
    ima[0] = (float)v[3]; ima[1] = (float)v[4]; ima[2] = (float)v[5];
  }
  float* o_n = out;
  float* o_a = out + (size_t)P * 3;
  float* o_p = out + (size_t)P * 6;
  float* o_i = o_p + P;
  o_n[(size_t)p * 3 + 0] = imn[0];
  o_n[(size_t)p * 3 + 1] = imn[1];
  o_n[(size_t)p * 3 + 2] = imn[2];
  o_a[(size_t)p * 3 + 0] = ima[0];
  o_a[(size_t)p * 3 + 1] = ima[1];
  o_a[(size_t)p * 3 + 2] = ima[2];
  o_i[p] = covered ? (float)best : -1.0f;
}

__global__ void k_final(const float* __restrict__ vs_cam,
                        const int* __restrict__ faces,
                        const float* __restrict__ vnorm,
                        const float* __restrict__ attribs,
                        const float4* __restrict__ pc,
                        float* __restrict__ out,
                        int* __restrict__ cnt, int* __restrict__ list,
                        int B, int V, int F, int NC) {
  int p = blockIdx.x * blockDim.x + threadIdx.x;
  int P = B * HW * HW;
  if (p >= P) return;
  float zmin = INFINITY, weps = 0.f, lsum = 0.f;
  int best = 0;
  bool flag = false;
  for (int c = 0; c < NC; ++c) {
    float4 q = pc[(size_t)c * P + p];
    float z = q.x;
    float e = q.z;
    unsigned pb = __float_as_uint(q.w);
    flag |= (pb >> 31) != 0;
    flag |= fabsf(z - zmin) < (e + weps + 2e-6f);  // cross-chunk near-tie (NaN-safe)
    if (z < zmin) { zmin = z; best = (int)(pb & 0x7fffffffu); weps = e; }
    lsum += q.y;
  }
  bool covered = (zmin < 1e38f);
  int b = p >> 12;            // HW*HW = 4096
  int pix = p & 4095;
  write_winner(vs_cam, faces, vnorm, attribs, out, P, b, V, F, pix, best, covered);
  float* o_p = out + (size_t)P * 6;
  o_p[p] = 1.0f - __expf(lsum);
  if (flag) {
    int s = atomicAdd(cnt, 1);
    list[s] = p;
  }
}

// exact f64 re-argmin for flagged pixels: ONE BLOCK (4 waves, 256 lanes) per
// pixel (R16: 4x shorter serial chain than wave-per-pixel; branchless body —
// the only repair structure that ever pipelined, R12-proven).
__global__ __launch_bounds__(256) void k_repair(
    const float* __restrict__ vs_cam,
    const int* __restrict__ faces,
    const float* __restrict__ vnorm,
    const float* __restrict__ attribs,
    const int* __restrict__ cnt, const int* __restrict__ list,
    float* __restrict__ out, int B, int V, int F) {
  __shared__ double zred[4];
  __shared__ int bred[4];
  int P = B * HW * HW;
  int tid = threadIdx.x;
  int wv = tid >> 6;
  int lane = tid & 63;
  int n = cnt[0];
  for (int i = blockIdx.x; i < n; i += gridDim.x) {
    int p = list[i];
    int b = p >> 12;
    int pix = p & 4095;
    int x = pix & 63, y = pix >> 6;
    const double step = 2.0 / 63.0;
    double px = (x == HW - 1) ? 1.0 : (x * step - 1.0);
    double py = (y == HW - 1) ? 1.0 : (y * step - 1.0);
    double zmin = INFINITY;
    int best = 0x7fffffff;
    for (int f = tid; f < F; f += 256) {     // 256-lane stride: chain / 4
      int i0 = faces[f * 3 + 0], i1 = faces[f * 3 + 1], i2 = faces[f * 3 + 2];
      const float* c0 = vs_cam + (size_t)(b * V + i0) * 3;
      const float* c1 = vs_cam + (size_t)(b * V + i1) * 3;
      const float* c2 = vs_cam + (size_t)(b * V + i2) * 3;
      float c0z = c0[2], c1z = c1[2], c2z = c2[2];
      float v0x = c0[0] / c0z, v0y = c0[1] / c0z;
      float v1x = c1[0] / c1z, v1y = c1[1] / c1z;
      float v2x = c2[0] / c2z, v2y = c2[1] / c2z;
      float dx0 = v2x - v1x, dy0 = v2y - v1y;
      float dx1 = v0x - v2x, dy1 = v0y - v2y;
      float dx2 = v1x - v0x, dy2 = v1y - v0y;
      float A = dx2 * (v2y - v0y) - dy2 * (v2x - v0x);
      if (fabsf(A) < 1e-8f) A = 1e-8f;
      double invA = 1.0 / (double)A;
      double a0 = (double)dx0 * (py - (double)v1y) - (double)dy0 * (px - (double)v1x);
      double a1 = (double)dx1 * (py - (double)v2y) - (double)dy1 * (px - (double)v2x);
      double a2 = (double)dx2 * (py - (double)v0y) - (double)dy2 * (px - (double)v0x);
      double w0 = a0 * invA, w1 = a1 * invA, w2 = a2 * invA;
      bool inside = (w0 >= 0.0) & (w1 >= 0.0) & (w2 >= 0.0);
      double z = (w0 * (double)c0z + w1 * (double)c1z) + w2 * (double)c2z;
      // per-lane visits ascend in f; strict < keeps first occurrence
      if (inside & (z > 0.0) & (z < zmin)) { zmin = z; best = f; }
    }
    // lexicographic (z, idx) wave reduce
    for (int off = 32; off; off >>= 1) {
      double zo = __shfl_down(zmin, off);
      int bo = __shfl_down(best, off);
      if ((zo < zmin) || ((zo == zmin) && (bo < best))) { zmin = zo; best = bo; }
    }
    if (lane == 0) { zred[wv] = zmin; bred[wv] = best; }
    __syncthreads();
    if (tid == 0) {
      double zm = zred[0];
      int bs = bred[0];
#pragma unroll
      for (int k = 1; k < 4; ++k) {
        double zo = zred[k];
        int bo = bred[k];
        if ((zo < zm) || ((zo == zm) && (bo < bs))) { zm = zo; bs = bo; }
      }
      bool covered = (zm < 1e300);
      write_winner(vs_cam, faces, vnorm, attribs, out, P, b, V, F, pix, bs, covered);
    }
    __syncthreads();   // zred/bred reuse safety across grid-stride iterations
  }
}

extern "C" void kernel_launch(void* const* d_in, const int* in_sizes, int n_in,
                              void* d_out, int out_size, void* d_ws, size_t ws_size,
                              hipStream_t stream) {
  const float* vert    = (const float*)d_in[0];
  const int*   faces   = (const int*)d_in[1];
  const float* attribs = (const float*)d_in[2];
  const float* rot     = (const float*)d_in[3];
  const float* trans   = (const float*)d_in[4];
  int B = in_sizes[4] / 3;
  int V = in_sizes[0] / (3 * B);
  int F = in_sizes[1] / 3;
  int P = B * HW * HW;
  int NR = B * HW;                              // total (b,row) buckets

  size_t CAP = (size_t)F;                       // exact worst case, no overflow
  size_t szFras  = sizeof(FaceRasF) * (size_t)B * F;
  size_t szBuk   = 4ull * (size_t)NR * CAP;
  size_t szVs    = 12ull * (size_t)B * V;
  size_t szVn    = 12ull * (size_t)B * V;
  size_t szRowC  = 4ull * (size_t)NR * CSTR;    // rowcnt (strided)
  size_t szCnt   = 4;
  size_t szPlist = 4ull * (size_t)P;
  size_t fixed   = szFras + szBuk + szVs + szVn + szRowC + szCnt + szPlist + 1024;

  int NC = 32;                                  // chunks
  while (NC > 2 && fixed + (size_t)P * 16ull * NC > ws_size) NC >>= 1;

  char* w = (char*)d_ws;
  FaceRasF* frasF  = (FaceRasF*)w; w += szFras;            // 64B-aligned
  float4* pc       = (float4*)w;   w += (size_t)P * 16ull * NC;
  unsigned* rowbuk = (unsigned*)w; w += szBuk;
  float* vs_cam    = (float*)w;    w += szVs;
  float* vnorm     = (float*)w;    w += szVn;
  unsigned* rowcnt = (unsigned*)w; w += szRowC;            // contiguous zero region:
  int* cnt         = (int*)w;      w += szCnt;             //   rowcnt + cnt
  int* list        = (int*)w;      /* P entries */
  int nzero = NR * CSTR + 1;

  k_prep<<<(B * V + 255) / 256, 256, 0, stream>>>(vert, rot, trans, vs_cam,
                                                  vnorm, rowcnt, nzero, B, V);
  dim3 fg((unsigned)((F + 255) / 256), (unsigned)B);
  k_facepre<<<fg, 256, 0, stream>>>(vs_cam, faces, frasF, vnorm, rowcnt,
                                    rowbuk, (unsigned)CAP, B, V, F);
  // 1-D chunk-fast grid: consecutive block IDs = chunks of the same pixgrp,
  // spread across CUs/XCDs; stride-16 rows inside blocks balance the rest.
  k_raster<<<(unsigned)(B * PPB * NC), 256, 0, stream>>>(frasF, rowcnt, rowbuk,
                                                         pc, (unsigned)CAP, F,
                                                         NC, P);
  k_final<<<(P + 255) / 256, 256, 0, stream>>>(vs_cam, faces, vnorm, attribs,
                                               pc, (float*)d_out, cnt, list,
                                               B, V, F, NC);
  k_repair<<<2048, 256, 0, stream>>>(vs_cam, faces, vnorm, attribs,
                                     cnt, list, (float*)d_out, B, V, F);
}